// Round 7
// baseline (2496.820 us; speedup 1.0000x reference)
//
#include <hip/hip_runtime.h>
#include <math.h>

#define N_NODES 50000
#define N_EDGES 200000
#define N_GRAPHS 128
#define M_PAD 50048   // N_NODES rounded up to 128

typedef short s16x8 __attribute__((ext_vector_type(8)));
typedef float f32x4 __attribute__((ext_vector_type(4)));

// ---------------- persistent private scratch (allocated at dlopen, NOT in kernel_launch) ----
static void* g_scratch = nullptr;
struct ScratchInit {
    ScratchInit() {
        if (hipMalloc(&g_scratch, (size_t)704 * 1024 * 1024) != hipSuccess) g_scratch = nullptr;
    }
};
static ScratchInit g_scratch_init;

// ---------------- bf16 helpers ----------------
__device__ __forceinline__ unsigned short f2bf_rn(float x) {
    unsigned u = __float_as_uint(x);
    unsigned r = (u + 0x7FFFu + ((u >> 16) & 1u)) >> 16;
    return (unsigned short)r;
}
__device__ __forceinline__ float bf2f(unsigned short h) {
    return __uint_as_float(((unsigned)h) << 16);
}

__device__ __forceinline__ void gl_lds16(const void* g, void* l) {
    __builtin_amdgcn_global_load_lds((const __attribute__((address_space(1))) unsigned int*)g,
                                     (__attribute__((address_space(3))) unsigned int*)l, 16, 0, 0);
}

// ---------------- zero a region ----------------
__global__ void k_zero(int* __restrict__ p, int n) {
    int i = blockIdx.x * 256 + threadIdx.x;
    if (i < n) p[i] = 0;
}

// ---------------- edge-weight MLP ----------------
__global__ void k_edge_mlp(const float* __restrict__ ea, const float* __restrict__ w1,
                           const float* __restrict__ b1, const float* __restrict__ w2,
                           const float* __restrict__ b2, float* __restrict__ ew, int E) {
    int e = blockIdx.x * 256 + threadIdx.x;
    if (e >= E) return;
    float a0 = ea[e * 3 + 0], a1 = ea[e * 3 + 1], a2 = ea[e * 3 + 2];
    float acc = b2[0];
#pragma unroll
    for (int j = 0; j < 64; j++) {
        float h = fmaf(a0, w1[j], fmaf(a1, w1[64 + j], fmaf(a2, w1[128 + j], b1[j])));
        h = fmaxf(h, 0.0f);
        acc = fmaf(h, w2[j], acc);
    }
    ew[e] = 1.0f / (1.0f + expf(-acc));
}

// ---------------- degree + histogram ----------------
__global__ void k_deg(const int* __restrict__ dst, const float* __restrict__ ew,
                      float* __restrict__ degf, int* __restrict__ counts, int E) {
    int e = blockIdx.x * 256 + threadIdx.x;
    if (e >= E) return;
    unsigned d = (unsigned)dst[e];
    if (d >= N_NODES) return;
    atomicAdd(&degf[d], ew[e]);
    atomicAdd(&counts[d], 1);
}

__global__ void k_dis(const float* __restrict__ degf, float* __restrict__ dis,
                      float* __restrict__ selfn, int n) {
    int i = blockIdx.x * 256 + threadIdx.x;
    if (i >= n) return;
    float d = degf[i] + 1.0f;
    float r = (float)(1.0 / sqrt((double)d));
    dis[i] = r;
    selfn[i] = r * r;
}

// ---------------- single-block scan ----------------
__global__ void k_scan(const int* __restrict__ counts, int* __restrict__ row_ptr, int n) {
    __shared__ int buf[1024];
    __shared__ int carry;
    int t = threadIdx.x;
    if (t == 0) { carry = 0; row_ptr[0] = 0; }
    __syncthreads();
    for (int base = 0; base < n; base += 1024) {
        int i = base + t;
        int v = (i < n) ? counts[i] : 0;
        buf[t] = v;
        __syncthreads();
        for (int offs = 1; offs < 1024; offs <<= 1) {
            int add = (t >= offs) ? buf[t - offs] : 0;
            __syncthreads();
            buf[t] += add;
            __syncthreads();
        }
        int incl = buf[t] + carry;
        if (i < n) row_ptr[i + 1] = incl;
        int total = buf[1023];
        __syncthreads();
        if (t == 0) carry += total;
        __syncthreads();
    }
}

// ---------------- CSR scatter ----------------
__global__ void k_scatter(const int* __restrict__ src, const int* __restrict__ dst,
                          const float* __restrict__ ew, const float* __restrict__ dis,
                          const int* __restrict__ row_ptr, int* __restrict__ cursor,
                          int* __restrict__ colsrc, float* __restrict__ normw, int E) {
    int e = blockIdx.x * 256 + threadIdx.x;
    if (e >= E) return;
    unsigned d = (unsigned)dst[e], s = (unsigned)src[e];
    if (d >= N_NODES || s >= N_NODES) return;
    int pos = row_ptr[d] + atomicAdd(&cursor[d], 1);
    if ((unsigned)pos >= N_EDGES) return;
    colsrc[pos] = (int)s;
    normw[pos] = dis[s] * ew[e] * dis[d];
}

// ---------------- per-graph counts ----------------
__global__ void k_gcount(const int* __restrict__ batch, int* __restrict__ gcnt, int n) {
    int i = blockIdx.x * 256 + threadIdx.x;
    if (i >= n) return;
    unsigned b = (unsigned)batch[i];
    if (b < N_GRAPHS) atomicAdd(&gcnt[b], 1);
}

__global__ void k_gscan(const int* __restrict__ gcnt, int* __restrict__ gstart) {
    if (threadIdx.x == 0 && blockIdx.x == 0) {
        int s = 0;
        for (int g = 0; g < N_GRAPHS; g++) { gstart[g] = s; s += gcnt[g]; }
    }
}

// ---------------- weight split+transpose: W[K][N] f32 -> Bt_hi/Bt_lo[N][K] bf16 ----------------
__global__ void k_wsplit_t(const float* __restrict__ W, short* __restrict__ Bth,
                           short* __restrict__ Btl, int K, int N) {
    __shared__ float t[32][33];
    int tx = threadIdx.x % 32, ty = threadIdx.x / 32;   // 32 x 8
    int bx = blockIdx.x, by = blockIdx.y;
#pragma unroll
    for (int i = 0; i < 4; i++) {
        int k = by * 32 + ty + i * 8;
        t[ty + i * 8][tx] = W[(size_t)k * N + bx * 32 + tx];
    }
    __syncthreads();
#pragma unroll
    for (int i = 0; i < 4; i++) {
        int n = bx * 32 + ty + i * 8;
        int k = by * 32 + tx;
        float v = t[tx][ty + i * 8];
        unsigned short h = f2bf_rn(v);
        Bth[(size_t)n * K + k] = (short)h;
        Btl[(size_t)n * K + k] = (short)f2bf_rn(v - bf2f(h));
    }
}

// ---------------- fp32 tiled GEMM (emb1), epilogue writes split bf16 ----------------
__launch_bounds__(256)
__global__ void gemm_tile_split(const float* __restrict__ A, const float* __restrict__ B,
                                const float* __restrict__ bias, short* __restrict__ Chi,
                                short* __restrict__ Clo, int M, int K, int N) {
    constexpr int BM = 128, BN = 128, BK = 8, TM = 8, TN = 8;
    __shared__ float As[BK * BM];
    __shared__ float Bs[BK * BN];
    int tid = threadIdx.x;
    int tx = tid % (BN / TN);
    int ty = tid / (BN / TN);
    int m0 = blockIdx.y * BM, n0 = blockIdx.x * BN;
    float acc[TM][TN] = {};
    int arow = tid / 2;
    int acol = (tid % 2) * 4;
    int brow = tid / 32;
    int bcol = (tid % 32) * 4;
    for (int k0 = 0; k0 < K; k0 += BK) {
        float4 av = make_float4(0.f, 0.f, 0.f, 0.f);
        int gr = m0 + arow;
        if (gr < M) av = *(const float4*)(A + (size_t)gr * K + k0 + acol);
        As[(acol + 0) * BM + arow] = av.x;
        As[(acol + 1) * BM + arow] = av.y;
        As[(acol + 2) * BM + arow] = av.z;
        As[(acol + 3) * BM + arow] = av.w;
        float4 bv = *(const float4*)(B + (size_t)(k0 + brow) * N + n0 + bcol);
        *(float4*)(Bs + brow * BN + bcol) = bv;
        __syncthreads();
#pragma unroll
        for (int kk = 0; kk < BK; kk++) {
            float a[TM], b[TN];
#pragma unroll
            for (int i = 0; i < TM; i += 4)
                *(float4*)(a + i) = *(const float4*)(As + kk * BM + ty * TM + i);
#pragma unroll
            for (int j = 0; j < TN; j += 4)
                *(float4*)(b + j) = *(const float4*)(Bs + kk * BN + tx * TN + j);
#pragma unroll
            for (int i = 0; i < TM; i++)
#pragma unroll
                for (int j = 0; j < TN; j++)
                    acc[i][j] = fmaf(a[i], b[j], acc[i][j]);
        }
        __syncthreads();
    }
#pragma unroll
    for (int i = 0; i < TM; i++) {
        int r = m0 + ty * TM + i;
        if (r >= M) continue;
#pragma unroll
        for (int j = 0; j < TN; j += 4) {
            int c = n0 + tx * TN + j;
            short4 hv, lv;
            float vv[4];
#pragma unroll
            for (int q = 0; q < 4; q++) {
                float v = acc[i][j + q] + bias[c + q];
                vv[q] = fmaxf(v, 0.f);
            }
            hv.x = (short)f2bf_rn(vv[0]); hv.y = (short)f2bf_rn(vv[1]);
            hv.z = (short)f2bf_rn(vv[2]); hv.w = (short)f2bf_rn(vv[3]);
            lv.x = (short)f2bf_rn(vv[0] - bf2f(hv.x));
            lv.y = (short)f2bf_rn(vv[1] - bf2f(hv.y));
            lv.z = (short)f2bf_rn(vv[2] - bf2f(hv.z));
            lv.w = (short)f2bf_rn(vv[3] - bf2f(hv.w));
            *(short4*)(Chi + (size_t)r * N + c) = hv;
            *(short4*)(Clo + (size_t)r * N + c) = lv;
        }
    }
}

// ---------------- bf16x3 MFMA GEMM, 128x128 tile, 256 threads -------------------------------
// A (M_PAD x K) hi/lo bf16, B^T (N x K) hi/lo bf16.
// EPI 1: +bias, relu, write split bf16.  EPI 2: +bias, relu, write f32.
// PLAIN x-fastest mapping (round-3 proven): with nbx=8, lid%8==blockIdx.x, so under
// round-robin XCD dispatch each XCD owns one B-column (L2-resident) and the 8 XCDs
// stream the same A-panel co-timed from HBM/L3 — measured fastest variant
// (340us @ MfmaUtil 41.5%); both L3-oriented swizzles regressed (r5/r6: ~435us).
template <int EPI>
__launch_bounds__(256)
__global__ void gemm_mf(const short* __restrict__ Ah, const short* __restrict__ Al,
                        const short* __restrict__ Bh, const short* __restrict__ Bl,
                        const float* __restrict__ bias, float* __restrict__ C,
                        short* __restrict__ Chi, short* __restrict__ Clo,
                        int M, int K, int N) {
    __shared__ short lds[4 * 4096];           // 32 KB
    short* lA_h = lds;
    short* lA_l = lds + 4096;
    short* lB_h = lds + 8192;
    short* lB_l = lds + 12288;
    int tid = threadIdx.x, lane = tid & 63, wave = tid >> 6;
    int wm = wave >> 1, wn = wave & 1;
    int q4 = lane >> 4, l15 = lane & 15;
    int m0 = blockIdx.y * 128, n0 = blockIdx.x * 128;

    f32x4 acc[4][4] = {};

    for (int k0 = 0; k0 < K; k0 += 32) {
        __syncthreads();
#pragma unroll
        for (int it = 0; it < 8; ++it) {
            int arr = it >> 1;
            int ca = ((it & 1) << 8) + tid;          // chunk within array, 0..511
            int r = ca >> 2, slot = ca & 3;
            int q = slot ^ ((r >> 1) & 3);           // xor-swizzle: conflict-free frag reads
            int grow = (arr < 2) ? (m0 + r) : (n0 + r);
            const short* gb = (arr == 0) ? Ah : (arr == 1) ? Al : (arr == 2) ? Bh : Bl;
            const short* g = gb + (size_t)grow * K + k0 + q * 8;
            int chunk_base = ((it & 1) << 8) + (wave << 6);   // wave-uniform
            short* l = lds + arr * 4096 + chunk_base * 8;
            gl_lds16(g, l);
        }
        __syncthreads();
        s16x8 a_h[4], a_l[4], b_h[4], b_l[4];
#pragma unroll
        for (int t = 0; t < 4; ++t) {
            int rA = wm * 64 + t * 16 + l15;
            int pA = rA * 4 + (q4 ^ ((rA >> 1) & 3));
            a_h[t] = *(const s16x8*)(lA_h + pA * 8);
            a_l[t] = *(const s16x8*)(lA_l + pA * 8);
            int rB = wn * 64 + t * 16 + l15;
            int pB = rB * 4 + (q4 ^ ((rB >> 1) & 3));
            b_h[t] = *(const s16x8*)(lB_h + pB * 8);
            b_l[t] = *(const s16x8*)(lB_l + pB * 8);
        }
#pragma unroll
        for (int tm = 0; tm < 4; ++tm)
#pragma unroll
            for (int tn = 0; tn < 4; ++tn) {
                acc[tm][tn] = __builtin_amdgcn_mfma_f32_16x16x32_bf16(a_h[tm], b_h[tn], acc[tm][tn], 0, 0, 0);
                acc[tm][tn] = __builtin_amdgcn_mfma_f32_16x16x32_bf16(a_h[tm], b_l[tn], acc[tm][tn], 0, 0, 0);
                acc[tm][tn] = __builtin_amdgcn_mfma_f32_16x16x32_bf16(a_l[tm], b_h[tn], acc[tm][tn], 0, 0, 0);
            }
    }
    // epilogue: C/D layout col=lane&15, row=(lane>>4)*4+reg
#pragma unroll
    for (int tm = 0; tm < 4; ++tm) {
#pragma unroll
        for (int tn = 0; tn < 4; ++tn) {
            int col = n0 + wn * 64 + tn * 16 + l15;
#pragma unroll
            for (int r = 0; r < 4; ++r) {
                int row = m0 + wm * 64 + tm * 16 + q4 * 4 + r;
                if (row < M) {
                    float v = acc[tm][tn][r] + bias[col];
                    v = fmaxf(v, 0.f);
                    if (EPI == 2) {
                        C[(size_t)row * N + col] = v;
                    } else {
                        unsigned short h2 = f2bf_rn(v);
                        Chi[(size_t)row * N + col] = (short)h2;
                        Clo[(size_t)row * N + col] = (short)f2bf_rn(v - bf2f(h2));
                    }
                }
            }
        }
    }
}

// ---------------- CSR aggregation, split-in / split-out (agg-first, no bias/relu) -----------
template <int F>
__global__ void k_agg_s(const short* __restrict__ in_hi, const short* __restrict__ in_lo,
                        short* __restrict__ out_hi, short* __restrict__ out_lo,
                        const int* __restrict__ row_ptr, const int* __restrict__ colsrc,
                        const float* __restrict__ normw, const float* __restrict__ selfn) {
    int i = blockIdx.x;
    int t = threadIdx.x;
    size_t o = (size_t)i * F + t * 4;
    short4 h4 = *(const short4*)(in_hi + o);
    short4 l4 = *(const short4*)(in_lo + o);
    float sn = selfn[i];
    float a0 = sn * (bf2f((unsigned short)h4.x) + bf2f((unsigned short)l4.x));
    float a1 = sn * (bf2f((unsigned short)h4.y) + bf2f((unsigned short)l4.y));
    float a2 = sn * (bf2f((unsigned short)h4.z) + bf2f((unsigned short)l4.z));
    float a3 = sn * (bf2f((unsigned short)h4.w) + bf2f((unsigned short)l4.w));
    int e = row_ptr[i], eend = row_ptr[i + 1];
    for (; e < eend; ++e) {
        unsigned s = (unsigned)colsrc[e];
        if (s >= N_NODES) continue;
        float w = normw[e];
        size_t os = (size_t)s * F + t * 4;
        short4 uh = *(const short4*)(in_hi + os);
        short4 ul = *(const short4*)(in_lo + os);
        a0 = fmaf(w, bf2f((unsigned short)uh.x) + bf2f((unsigned short)ul.x), a0);
        a1 = fmaf(w, bf2f((unsigned short)uh.y) + bf2f((unsigned short)ul.y), a1);
        a2 = fmaf(w, bf2f((unsigned short)uh.z) + bf2f((unsigned short)ul.z), a2);
        a3 = fmaf(w, bf2f((unsigned short)uh.w) + bf2f((unsigned short)ul.w), a3);
    }
    short4 hv, lv;
    hv.x = (short)f2bf_rn(a0); hv.y = (short)f2bf_rn(a1);
    hv.z = (short)f2bf_rn(a2); hv.w = (short)f2bf_rn(a3);
    lv.x = (short)f2bf_rn(a0 - bf2f((unsigned short)hv.x));
    lv.y = (short)f2bf_rn(a1 - bf2f((unsigned short)hv.y));
    lv.z = (short)f2bf_rn(a2 - bf2f((unsigned short)hv.z));
    lv.w = (short)f2bf_rn(a3 - bf2f((unsigned short)hv.w));
    *(short4*)(out_hi + o) = hv;
    *(short4*)(out_lo + o) = lv;
}

// ---------------- mean-pool (double accumulation) ----------------
__global__ void k_pool(const float4* __restrict__ h, const int* __restrict__ gstart,
                       const int* __restrict__ gcnt, float* __restrict__ pooled) {
    int g = blockIdx.x;
    int t = threadIdx.x;
    int beg = gstart[g], cnt = gcnt[g];
    if (beg + cnt > N_NODES) cnt = N_NODES - beg;
    double a0 = 0, a1 = 0, a2 = 0, a3 = 0;
    for (int n = 0; n < cnt; n++) {
        float4 v = h[(size_t)(beg + n) * 256 + t];
        a0 += v.x; a1 += v.y; a2 += v.z; a3 += v.w;
    }
    float inv = 1.0f / fmaxf((float)gcnt[g], 1.0f);
    pooled[g * 1024 + t * 4 + 0] = (float)a0 * inv;
    pooled[g * 1024 + t * 4 + 1] = (float)a1 * inv;
    pooled[g * 1024 + t * 4 + 2] = (float)a2 * inv;
    pooled[g * 1024 + t * 4 + 3] = (float)a3 * inv;
}

// ---------------- small GEMM (M=128), double accumulation ----------------
template <bool RELU>
__global__ void gemm_small(const float* __restrict__ A, const float* __restrict__ B,
                           const float* __restrict__ bias, float* __restrict__ C,
                           int K, int N) {
    int n = blockIdx.x * 256 + threadIdx.x;
    int m = blockIdx.y;
    if (n >= N) return;
    const float* a = A + (size_t)m * K;
    double acc = 0.0;
    for (int k = 0; k < K; k += 4) {
        acc += (double)a[k] * (double)B[(size_t)k * N + n];
        acc += (double)a[k + 1] * (double)B[(size_t)(k + 1) * N + n];
        acc += (double)a[k + 2] * (double)B[(size_t)(k + 2) * N + n];
        acc += (double)a[k + 3] * (double)B[(size_t)(k + 3) * N + n];
    }
    float r = (float)acc + bias[n];
    if (RELU) r = fmaxf(r, 0.0f);
    C[(size_t)m * N + n] = r;
}

extern "C" void kernel_launch(void* const* d_in, const int* in_sizes, int n_in,
                              void* d_out, int out_size, void* d_ws, size_t ws_size,
                              hipStream_t stream) {
    const float* x      = (const float*)d_in[0];
    const float* eattr  = (const float*)d_in[1];
    const int*   eidx   = (const int*)d_in[2];
    const int*   batch  = (const int*)d_in[3];
    const float* emb_w1 = (const float*)d_in[4];
    const float* emb_b1 = (const float*)d_in[5];
    const float* emb_w2 = (const float*)d_in[6];
    const float* emb_b2 = (const float*)d_in[7];
    const float* ep_w1  = (const float*)d_in[8];
    const float* ep_b1  = (const float*)d_in[9];
    const float* ep_w2  = (const float*)d_in[10];
    const float* ep_b2  = (const float*)d_in[11];
    const float* c6_w   = (const float*)d_in[12];
    const float* c6_b   = (const float*)d_in[13];
    const float* c7_w   = (const float*)d_in[14];
    const float* c7_b   = (const float*)d_in[15];
    const float* c8_w   = (const float*)d_in[16];
    const float* c8_b   = (const float*)d_in[17];
    const float* fc1_w  = (const float*)d_in[18];
    const float* fc1_b  = (const float*)d_in[19];
    const float* head_w = (const float*)d_in[20];
    const float* head_b = (const float*)d_in[21];
    float* out = (float*)d_out;

    const int* src = eidx;
    const int* dst = eidx + N_EDGES;

    // ---- workspace layout (bytes) ----
    size_t off = 0;
    auto lay = [&](size_t nbytes) -> size_t {
        size_t p = off;
        off += (nbytes + 255) & ~(size_t)255;
        return p;
    };
    size_t ob0  = lay((size_t)M_PAD * 1024 * 4);   // ping: split pair (hi|lo) or f32
    size_t ob1  = lay((size_t)M_PAD * 1024 * 4);   // pong
    size_t oBt2 = lay((size_t)512 * 512 * 2 * 2);
    size_t oBt6 = lay((size_t)1024 * 512 * 2 * 2);
    size_t oBt7 = lay((size_t)1024 * 1024 * 2 * 2);
    size_t oBt8 = lay((size_t)1024 * 1024 * 2 * 2);
    size_t oew     = lay(N_EDGES * 4);
    size_t odis    = lay(N_NODES * 4);
    size_t oselfn  = lay(N_NODES * 4);
    size_t onormw  = lay(N_EDGES * 4);
    size_t opooled = lay((size_t)N_GRAPHS * 1024 * 4);
    size_t oz      = lay((size_t)N_GRAPHS * 2048 * 4);
    size_t zbeg = off;
    size_t odegf   = lay(N_NODES * 4);
    size_t ocounts = lay(N_NODES * 4);
    size_t ocursor = lay(N_NODES * 4);
    size_t ogcnt   = lay(N_GRAPHS * 4);
    size_t zend = off;
    size_t orowp   = lay((N_NODES + 1) * 4);
    size_t ocolsrc = lay(N_EDGES * 4);
    size_t ogstart = lay(N_GRAPHS * 4);
    size_t need_bytes = off;

    char* base = (ws_size >= need_bytes) ? (char*)d_ws : (char*)g_scratch;

    short* b0 = (short*)(base + ob0);
    short* b1 = (short*)(base + ob1);
    // 512-wide split pairs
    short* S1h = b0;                       short* S1l = b0 + (size_t)M_PAD * 512;
    short* S2h = b1;                       short* S2l = b1 + (size_t)M_PAD * 512;
    short* A6h = b0;                       short* A6l = b0 + (size_t)M_PAD * 512;
    // 1024-wide split pairs
    short* S3h = b1;                       short* S3l = b1 + (size_t)M_PAD * 1024;
    short* A7h = b0;                       short* A7l = b0 + (size_t)M_PAD * 1024;
    short* S4h = b1;                       short* S4l = b1 + (size_t)M_PAD * 1024;
    short* A8h = b0;                       short* A8l = b0 + (size_t)M_PAD * 1024;
    float* Y   = (float*)b1;               // final conv output f32
    short* Bt2h = (short*)(base + oBt2);   short* Bt2l = Bt2h + (size_t)512 * 512;
    short* Bt6h = (short*)(base + oBt6);   short* Bt6l = Bt6h + (size_t)1024 * 512;
    short* Bt7h = (short*)(base + oBt7);   short* Bt7l = Bt7h + (size_t)1024 * 1024;
    short* Bt8h = (short*)(base + oBt8);   short* Bt8l = Bt8h + (size_t)1024 * 1024;
    float* ew     = (float*)(base + oew);
    float* dis    = (float*)(base + odis);
    float* selfn  = (float*)(base + oselfn);
    float* normw  = (float*)(base + onormw);
    float* pooled = (float*)(base + opooled);
    float* z      = (float*)(base + oz);
    float* degf   = (float*)(base + odegf);
    int*   counts = (int*)(base + ocounts);
    int*   cursor = (int*)(base + ocursor);
    int*   gcnt   = (int*)(base + ogcnt);
    int*   row_ptr= (int*)(base + orowp);
    int*   colsrc = (int*)(base + ocolsrc);
    int*   gstart = (int*)(base + ogstart);

    dim3 blk(256);
    int egrid = (N_EDGES + 255) / 256;
    int ngrid = (N_NODES + 255) / 256;
    int mtiles = M_PAD / 128;   // 391

    int nzero = (int)((zend - zbeg) / 4);
    k_zero<<<(nzero + 255) / 256, blk, 0, stream>>>((int*)(base + zbeg), nzero);

    // edge weights + CSR build
    k_edge_mlp<<<egrid, blk, 0, stream>>>(eattr, ep_w1, ep_b1, ep_w2, ep_b2, ew, N_EDGES);
    k_deg<<<egrid, blk, 0, stream>>>(dst, ew, degf, counts, N_EDGES);
    k_dis<<<ngrid, blk, 0, stream>>>(degf, dis, selfn, N_NODES);
    k_scan<<<1, 1024, 0, stream>>>(counts, row_ptr, N_NODES);
    k_scatter<<<egrid, blk, 0, stream>>>(src, dst, ew, dis, row_ptr, cursor, colsrc, normw, N_EDGES);
    k_gcount<<<ngrid, blk, 0, stream>>>(batch, gcnt, N_NODES);
    k_gscan<<<1, 64, 0, stream>>>(gcnt, gstart);

    // weight split+transpose
    k_wsplit_t<<<dim3(512 / 32, 512 / 32), blk, 0, stream>>>(emb_w2, Bt2h, Bt2l, 512, 512);
    k_wsplit_t<<<dim3(1024 / 32, 512 / 32), blk, 0, stream>>>(c6_w, Bt6h, Bt6l, 512, 1024);
    k_wsplit_t<<<dim3(1024 / 32, 1024 / 32), blk, 0, stream>>>(c7_w, Bt7h, Bt7l, 1024, 1024);
    k_wsplit_t<<<dim3(1024 / 32, 1024 / 32), blk, 0, stream>>>(c8_w, Bt8h, Bt8l, 1024, 1024);

    // emb1 (fp32): S1 = split(relu(x@emb_w1+b1))     [b0]
    gemm_tile_split<<<dim3(512 / 128, mtiles), blk, 0, stream>>>(x, emb_w1, emb_b1, S1h, S1l, N_NODES, 40, 512);

    // emb2: S2 = split(relu(S1@emb_w2+b2))           [b1]
    gemm_mf<1><<<dim3(512 / 128, mtiles), blk, 0, stream>>>(S1h, S1l, Bt2h, Bt2l, emb_b2,
                                                            nullptr, S2h, S2l, N_NODES, 512, 512);

    // conv6 (agg-first): A6 = agg(S2) [b0]; S3 = split(relu(A6@c6_w+b6)) [b1]
    k_agg_s<512><<<N_NODES, 128, 0, stream>>>(S2h, S2l, A6h, A6l, row_ptr, colsrc, normw, selfn);
    gemm_mf<1><<<dim3(1024 / 128, mtiles), blk, 0, stream>>>(A6h, A6l, Bt6h, Bt6l, c6_b,
                                                             nullptr, S3h, S3l, N_NODES, 512, 1024);

    // conv7: A7 = agg(S3) [b0]; S4 = split(relu(A7@c7_w+b7)) [b1]
    k_agg_s<1024><<<N_NODES, 256, 0, stream>>>(S3h, S3l, A7h, A7l, row_ptr, colsrc, normw, selfn);
    gemm_mf<1><<<dim3(1024 / 128, mtiles), blk, 0, stream>>>(A7h, A7l, Bt7h, Bt7l, c7_b,
                                                             nullptr, S4h, S4l, N_NODES, 1024, 1024);

    // conv8: A8 = agg(S4) [b0]; Y = relu(A8@c8_w+b8) f32 [b1]
    k_agg_s<1024><<<N_NODES, 256, 0, stream>>>(S4h, S4l, A8h, A8l, row_ptr, colsrc, normw, selfn);
    gemm_mf<2><<<dim3(1024 / 128, mtiles), blk, 0, stream>>>(A8h, A8l, Bt8h, Bt8l, c8_b,
                                                             Y, nullptr, nullptr, N_NODES, 1024, 1024);

    // pool + head
    k_pool<<<N_GRAPHS, blk, 0, stream>>>((const float4*)Y, gstart, gcnt, pooled);
    gemm_small<true><<<dim3((2048 + 255) / 256, N_GRAPHS), blk, 0, stream>>>(pooled, fc1_w, fc1_b, z, 1024, 2048);
    gemm_small<false><<<dim3((345 + 255) / 256, N_GRAPHS), blk, 0, stream>>>(z, head_w, head_b, out, 2048, 345);
}

// Round 8
// 2347.454 us; speedup vs baseline: 1.0636x; 1.0636x over previous
//
#include <hip/hip_runtime.h>
#include <math.h>

#define N_NODES 50000
#define N_EDGES 200000
#define N_GRAPHS 128
#define M_PAD 50048   // N_NODES rounded up to 128

typedef short s16x8 __attribute__((ext_vector_type(8)));
typedef float f32x4 __attribute__((ext_vector_type(4)));

// ---------------- persistent private scratch (allocated at dlopen, NOT in kernel_launch) ----
static void* g_scratch = nullptr;
struct ScratchInit {
    ScratchInit() {
        if (hipMalloc(&g_scratch, (size_t)704 * 1024 * 1024) != hipSuccess) g_scratch = nullptr;
    }
};
static ScratchInit g_scratch_init;

// ---------------- bf16 helpers ----------------
__device__ __forceinline__ unsigned short f2bf_rn(float x) {
    unsigned u = __float_as_uint(x);
    unsigned r = (u + 0x7FFFu + ((u >> 16) & 1u)) >> 16;
    return (unsigned short)r;
}
__device__ __forceinline__ float bf2f(unsigned short h) {
    return __uint_as_float(((unsigned)h) << 16);
}

__device__ __forceinline__ void gl_lds16(const void* g, void* l) {
    __builtin_amdgcn_global_load_lds((const __attribute__((address_space(1))) unsigned int*)g,
                                     (__attribute__((address_space(3))) unsigned int*)l, 16, 0, 0);
}

// ---------------- zero a region ----------------
__global__ void k_zero(int* __restrict__ p, int n) {
    int i = blockIdx.x * 256 + threadIdx.x;
    if (i < n) p[i] = 0;
}

// ---------------- edge-weight MLP ----------------
__global__ void k_edge_mlp(const float* __restrict__ ea, const float* __restrict__ w1,
                           const float* __restrict__ b1, const float* __restrict__ w2,
                           const float* __restrict__ b2, float* __restrict__ ew, int E) {
    int e = blockIdx.x * 256 + threadIdx.x;
    if (e >= E) return;
    float a0 = ea[e * 3 + 0], a1 = ea[e * 3 + 1], a2 = ea[e * 3 + 2];
    float acc = b2[0];
#pragma unroll
    for (int j = 0; j < 64; j++) {
        float h = fmaf(a0, w1[j], fmaf(a1, w1[64 + j], fmaf(a2, w1[128 + j], b1[j])));
        h = fmaxf(h, 0.0f);
        acc = fmaf(h, w2[j], acc);
    }
    ew[e] = 1.0f / (1.0f + expf(-acc));
}

// ---------------- degree + histogram ----------------
__global__ void k_deg(const int* __restrict__ dst, const float* __restrict__ ew,
                      float* __restrict__ degf, int* __restrict__ counts, int E) {
    int e = blockIdx.x * 256 + threadIdx.x;
    if (e >= E) return;
    unsigned d = (unsigned)dst[e];
    if (d >= N_NODES) return;
    atomicAdd(&degf[d], ew[e]);
    atomicAdd(&counts[d], 1);
}

__global__ void k_dis(const float* __restrict__ degf, float* __restrict__ dis,
                      float* __restrict__ selfn, int n) {
    int i = blockIdx.x * 256 + threadIdx.x;
    if (i >= n) return;
    float d = degf[i] + 1.0f;
    float r = (float)(1.0 / sqrt((double)d));
    dis[i] = r;
    selfn[i] = r * r;
}

// ---------------- single-block scan ----------------
__global__ void k_scan(const int* __restrict__ counts, int* __restrict__ row_ptr, int n) {
    __shared__ int buf[1024];
    __shared__ int carry;
    int t = threadIdx.x;
    if (t == 0) { carry = 0; row_ptr[0] = 0; }
    __syncthreads();
    for (int base = 0; base < n; base += 1024) {
        int i = base + t;
        int v = (i < n) ? counts[i] : 0;
        buf[t] = v;
        __syncthreads();
        for (int offs = 1; offs < 1024; offs <<= 1) {
            int add = (t >= offs) ? buf[t - offs] : 0;
            __syncthreads();
            buf[t] += add;
            __syncthreads();
        }
        int incl = buf[t] + carry;
        if (i < n) row_ptr[i + 1] = incl;
        int total = buf[1023];
        __syncthreads();
        if (t == 0) carry += total;
        __syncthreads();
    }
}

// ---------------- CSR scatter ----------------
__global__ void k_scatter(const int* __restrict__ src, const int* __restrict__ dst,
                          const float* __restrict__ ew, const float* __restrict__ dis,
                          const int* __restrict__ row_ptr, int* __restrict__ cursor,
                          int* __restrict__ colsrc, float* __restrict__ normw, int E) {
    int e = blockIdx.x * 256 + threadIdx.x;
    if (e >= E) return;
    unsigned d = (unsigned)dst[e], s = (unsigned)src[e];
    if (d >= N_NODES || s >= N_NODES) return;
    int pos = row_ptr[d] + atomicAdd(&cursor[d], 1);
    if ((unsigned)pos >= N_EDGES) return;
    colsrc[pos] = (int)s;
    normw[pos] = dis[s] * ew[e] * dis[d];
}

// ---------------- per-graph counts ----------------
__global__ void k_gcount(const int* __restrict__ batch, int* __restrict__ gcnt, int n) {
    int i = blockIdx.x * 256 + threadIdx.x;
    if (i >= n) return;
    unsigned b = (unsigned)batch[i];
    if (b < N_GRAPHS) atomicAdd(&gcnt[b], 1);
}

__global__ void k_gscan(const int* __restrict__ gcnt, int* __restrict__ gstart) {
    if (threadIdx.x == 0 && blockIdx.x == 0) {
        int s = 0;
        for (int g = 0; g < N_GRAPHS; g++) { gstart[g] = s; s += gcnt[g]; }
    }
}

// ---------------- weight split+transpose: W[K][N] f32 -> Bt_hi/Bt_lo[N][K] bf16 ----------------
__global__ void k_wsplit_t(const float* __restrict__ W, short* __restrict__ Bth,
                           short* __restrict__ Btl, int K, int N) {
    __shared__ float t[32][33];
    int tx = threadIdx.x % 32, ty = threadIdx.x / 32;   // 32 x 8
    int bx = blockIdx.x, by = blockIdx.y;
#pragma unroll
    for (int i = 0; i < 4; i++) {
        int k = by * 32 + ty + i * 8;
        t[ty + i * 8][tx] = W[(size_t)k * N + bx * 32 + tx];
    }
    __syncthreads();
#pragma unroll
    for (int i = 0; i < 4; i++) {
        int n = bx * 32 + ty + i * 8;
        int k = by * 32 + tx;
        float v = t[tx][ty + i * 8];
        unsigned short h = f2bf_rn(v);
        Bth[(size_t)n * K + k] = (short)h;
        Btl[(size_t)n * K + k] = (short)f2bf_rn(v - bf2f(h));
    }
}

// ---------------- fp32 tiled GEMM (emb1), epilogue writes split bf16 ----------------
__launch_bounds__(256)
__global__ void gemm_tile_split(const float* __restrict__ A, const float* __restrict__ B,
                                const float* __restrict__ bias, short* __restrict__ Chi,
                                short* __restrict__ Clo, int M, int K, int N) {
    constexpr int BM = 128, BN = 128, BK = 8, TM = 8, TN = 8;
    __shared__ float As[BK * BM];
    __shared__ float Bs[BK * BN];
    int tid = threadIdx.x;
    int tx = tid % (BN / TN);
    int ty = tid / (BN / TN);
    int m0 = blockIdx.y * BM, n0 = blockIdx.x * BN;
    float acc[TM][TN] = {};
    int arow = tid / 2;
    int acol = (tid % 2) * 4;
    int brow = tid / 32;
    int bcol = (tid % 32) * 4;
    for (int k0 = 0; k0 < K; k0 += BK) {
        float4 av = make_float4(0.f, 0.f, 0.f, 0.f);
        int gr = m0 + arow;
        if (gr < M) av = *(const float4*)(A + (size_t)gr * K + k0 + acol);
        As[(acol + 0) * BM + arow] = av.x;
        As[(acol + 1) * BM + arow] = av.y;
        As[(acol + 2) * BM + arow] = av.z;
        As[(acol + 3) * BM + arow] = av.w;
        float4 bv = *(const float4*)(B + (size_t)(k0 + brow) * N + n0 + bcol);
        *(float4*)(Bs + brow * BN + bcol) = bv;
        __syncthreads();
#pragma unroll
        for (int kk = 0; kk < BK; kk++) {
            float a[TM], b[TN];
#pragma unroll
            for (int i = 0; i < TM; i += 4)
                *(float4*)(a + i) = *(const float4*)(As + kk * BM + ty * TM + i);
#pragma unroll
            for (int j = 0; j < TN; j += 4)
                *(float4*)(b + j) = *(const float4*)(Bs + kk * BN + tx * TN + j);
#pragma unroll
            for (int i = 0; i < TM; i++)
#pragma unroll
                for (int j = 0; j < TN; j++)
                    acc[i][j] = fmaf(a[i], b[j], acc[i][j]);
        }
        __syncthreads();
    }
#pragma unroll
    for (int i = 0; i < TM; i++) {
        int r = m0 + ty * TM + i;
        if (r >= M) continue;
#pragma unroll
        for (int j = 0; j < TN; j += 4) {
            int c = n0 + tx * TN + j;
            short4 hv, lv;
            float vv[4];
#pragma unroll
            for (int q = 0; q < 4; q++) {
                float v = acc[i][j + q] + bias[c + q];
                vv[q] = fmaxf(v, 0.f);
            }
            hv.x = (short)f2bf_rn(vv[0]); hv.y = (short)f2bf_rn(vv[1]);
            hv.z = (short)f2bf_rn(vv[2]); hv.w = (short)f2bf_rn(vv[3]);
            lv.x = (short)f2bf_rn(vv[0] - bf2f(hv.x));
            lv.y = (short)f2bf_rn(vv[1] - bf2f(hv.y));
            lv.z = (short)f2bf_rn(vv[2] - bf2f(hv.z));
            lv.w = (short)f2bf_rn(vv[3] - bf2f(hv.w));
            *(short4*)(Chi + (size_t)r * N + c) = hv;
            *(short4*)(Clo + (size_t)r * N + c) = lv;
        }
    }
}

// ---------------- bf16x3 MFMA GEMM, 128x128 tile, 256 threads -------------------------------
// A (M_PAD x K) hi/lo bf16, B^T (N x K) hi/lo bf16.  C = relu(A@B + bias) as f32.
// The f32 dword-store epilogue is the PROVEN-FAST variant (r3: 340us, MfmaUtil 41.5%).
// Split bf16 epilogue (128 scattered 2-B stores/thread) cost +100us/GEMM (r4-r7) —
// the hi/lo split now lives in the aggregation kernel's coalesced epilogue instead.
__launch_bounds__(256)
__global__ void gemm_mf(const short* __restrict__ Ah, const short* __restrict__ Al,
                        const short* __restrict__ Bh, const short* __restrict__ Bl,
                        const float* __restrict__ bias, float* __restrict__ C,
                        int M, int K, int N) {
    __shared__ short lds[4 * 4096];           // 32 KB
    short* lA_h = lds;
    short* lA_l = lds + 4096;
    short* lB_h = lds + 8192;
    short* lB_l = lds + 12288;
    int tid = threadIdx.x, lane = tid & 63, wave = tid >> 6;
    int wm = wave >> 1, wn = wave & 1;
    int q4 = lane >> 4, l15 = lane & 15;
    int m0 = blockIdx.y * 128, n0 = blockIdx.x * 128;

    f32x4 acc[4][4] = {};

    for (int k0 = 0; k0 < K; k0 += 32) {
        __syncthreads();
#pragma unroll
        for (int it = 0; it < 8; ++it) {
            int arr = it >> 1;
            int ca = ((it & 1) << 8) + tid;          // chunk within array, 0..511
            int r = ca >> 2, slot = ca & 3;
            int q = slot ^ ((r >> 1) & 3);           // xor-swizzle: conflict-free frag reads
            int grow = (arr < 2) ? (m0 + r) : (n0 + r);
            const short* gb = (arr == 0) ? Ah : (arr == 1) ? Al : (arr == 2) ? Bh : Bl;
            const short* g = gb + (size_t)grow * K + k0 + q * 8;
            int chunk_base = ((it & 1) << 8) + (wave << 6);   // wave-uniform
            short* l = lds + arr * 4096 + chunk_base * 8;
            gl_lds16(g, l);
        }
        __syncthreads();
        s16x8 a_h[4], a_l[4], b_h[4], b_l[4];
#pragma unroll
        for (int t = 0; t < 4; ++t) {
            int rA = wm * 64 + t * 16 + l15;
            int pA = rA * 4 + (q4 ^ ((rA >> 1) & 3));
            a_h[t] = *(const s16x8*)(lA_h + pA * 8);
            a_l[t] = *(const s16x8*)(lA_l + pA * 8);
            int rB = wn * 64 + t * 16 + l15;
            int pB = rB * 4 + (q4 ^ ((rB >> 1) & 3));
            b_h[t] = *(const s16x8*)(lB_h + pB * 8);
            b_l[t] = *(const s16x8*)(lB_l + pB * 8);
        }
#pragma unroll
        for (int tm = 0; tm < 4; ++tm)
#pragma unroll
            for (int tn = 0; tn < 4; ++tn) {
                acc[tm][tn] = __builtin_amdgcn_mfma_f32_16x16x32_bf16(a_h[tm], b_h[tn], acc[tm][tn], 0, 0, 0);
                acc[tm][tn] = __builtin_amdgcn_mfma_f32_16x16x32_bf16(a_h[tm], b_l[tn], acc[tm][tn], 0, 0, 0);
                acc[tm][tn] = __builtin_amdgcn_mfma_f32_16x16x32_bf16(a_l[tm], b_h[tn], acc[tm][tn], 0, 0, 0);
            }
    }
    // epilogue: C/D layout col=lane&15, row=(lane>>4)*4+reg
#pragma unroll
    for (int tm = 0; tm < 4; ++tm) {
#pragma unroll
        for (int tn = 0; tn < 4; ++tn) {
            int col = n0 + wn * 64 + tn * 16 + l15;
#pragma unroll
            for (int r = 0; r < 4; ++r) {
                int row = m0 + wm * 64 + tm * 16 + q4 * 4 + r;
                if (row < M) {
                    float v = acc[tm][tn][r] + bias[col];
                    C[(size_t)row * N + col] = fmaxf(v, 0.f);
                }
            }
        }
    }
}

// ---------------- CSR aggregation: f32 in -> split bf16 out (agg-first, no bias/relu) -------
// out[i] = selfn[i]*x[i] + sum_e w_e*x[src_e].  F/4 threads per node, float4 gathers,
// coalesced short4 split stores.
template <int F>
__global__ void k_agg_f(const float* __restrict__ in, short* __restrict__ out_hi,
                        short* __restrict__ out_lo, const int* __restrict__ row_ptr,
                        const int* __restrict__ colsrc, const float* __restrict__ normw,
                        const float* __restrict__ selfn) {
    int i = blockIdx.x;
    int t = threadIdx.x;
    size_t o = (size_t)i * F + t * 4;
    float4 v = *(const float4*)(in + o);
    float sn = selfn[i];
    float a0 = sn * v.x, a1 = sn * v.y, a2 = sn * v.z, a3 = sn * v.w;
    int e = row_ptr[i], eend = row_ptr[i + 1];
    for (; e < eend; ++e) {
        unsigned s = (unsigned)colsrc[e];
        if (s >= N_NODES) continue;
        float w = normw[e];
        float4 u = *(const float4*)(in + (size_t)s * F + t * 4);
        a0 = fmaf(w, u.x, a0); a1 = fmaf(w, u.y, a1);
        a2 = fmaf(w, u.z, a2); a3 = fmaf(w, u.w, a3);
    }
    short4 hv, lv;
    hv.x = (short)f2bf_rn(a0); hv.y = (short)f2bf_rn(a1);
    hv.z = (short)f2bf_rn(a2); hv.w = (short)f2bf_rn(a3);
    lv.x = (short)f2bf_rn(a0 - bf2f((unsigned short)hv.x));
    lv.y = (short)f2bf_rn(a1 - bf2f((unsigned short)hv.y));
    lv.z = (short)f2bf_rn(a2 - bf2f((unsigned short)hv.z));
    lv.w = (short)f2bf_rn(a3 - bf2f((unsigned short)hv.w));
    *(short4*)(out_hi + o) = hv;
    *(short4*)(out_lo + o) = lv;
}

// ---------------- mean-pool (double accumulation) ----------------
__global__ void k_pool(const float4* __restrict__ h, const int* __restrict__ gstart,
                       const int* __restrict__ gcnt, float* __restrict__ pooled) {
    int g = blockIdx.x;
    int t = threadIdx.x;
    int beg = gstart[g], cnt = gcnt[g];
    if (beg + cnt > N_NODES) cnt = N_NODES - beg;
    double a0 = 0, a1 = 0, a2 = 0, a3 = 0;
    for (int n = 0; n < cnt; n++) {
        float4 v = h[(size_t)(beg + n) * 256 + t];
        a0 += v.x; a1 += v.y; a2 += v.z; a3 += v.w;
    }
    float inv = 1.0f / fmaxf((float)gcnt[g], 1.0f);
    pooled[g * 1024 + t * 4 + 0] = (float)a0 * inv;
    pooled[g * 1024 + t * 4 + 1] = (float)a1 * inv;
    pooled[g * 1024 + t * 4 + 2] = (float)a2 * inv;
    pooled[g * 1024 + t * 4 + 3] = (float)a3 * inv;
}

// ---------------- small GEMM (M=128), double accumulation ----------------
template <bool RELU>
__global__ void gemm_small(const float* __restrict__ A, const float* __restrict__ B,
                           const float* __restrict__ bias, float* __restrict__ C,
                           int K, int N) {
    int n = blockIdx.x * 256 + threadIdx.x;
    int m = blockIdx.y;
    if (n >= N) return;
    const float* a = A + (size_t)m * K;
    double acc = 0.0;
    for (int k = 0; k < K; k += 4) {
        acc += (double)a[k] * (double)B[(size_t)k * N + n];
        acc += (double)a[k + 1] * (double)B[(size_t)(k + 1) * N + n];
        acc += (double)a[k + 2] * (double)B[(size_t)(k + 2) * N + n];
        acc += (double)a[k + 3] * (double)B[(size_t)(k + 3) * N + n];
    }
    float r = (float)acc + bias[n];
    if (RELU) r = fmaxf(r, 0.0f);
    C[(size_t)m * N + n] = r;
}

extern "C" void kernel_launch(void* const* d_in, const int* in_sizes, int n_in,
                              void* d_out, int out_size, void* d_ws, size_t ws_size,
                              hipStream_t stream) {
    const float* x      = (const float*)d_in[0];
    const float* eattr  = (const float*)d_in[1];
    const int*   eidx   = (const int*)d_in[2];
    const int*   batch  = (const int*)d_in[3];
    const float* emb_w1 = (const float*)d_in[4];
    const float* emb_b1 = (const float*)d_in[5];
    const float* emb_w2 = (const float*)d_in[6];
    const float* emb_b2 = (const float*)d_in[7];
    const float* ep_w1  = (const float*)d_in[8];
    const float* ep_b1  = (const float*)d_in[9];
    const float* ep_w2  = (const float*)d_in[10];
    const float* ep_b2  = (const float*)d_in[11];
    const float* c6_w   = (const float*)d_in[12];
    const float* c6_b   = (const float*)d_in[13];
    const float* c7_w   = (const float*)d_in[14];
    const float* c7_b   = (const float*)d_in[15];
    const float* c8_w   = (const float*)d_in[16];
    const float* c8_b   = (const float*)d_in[17];
    const float* fc1_w  = (const float*)d_in[18];
    const float* fc1_b  = (const float*)d_in[19];
    const float* head_w = (const float*)d_in[20];
    const float* head_b = (const float*)d_in[21];
    float* out = (float*)d_out;

    const int* src = eidx;
    const int* dst = eidx + N_EDGES;

    // ---- workspace layout (bytes) ----
    size_t off = 0;
    auto lay = [&](size_t nbytes) -> size_t {
        size_t p = off;
        off += (nbytes + 255) & ~(size_t)255;
        return p;
    };
    size_t ob0  = lay((size_t)M_PAD * 1024 * 4);   // ping: split pair (hi|lo)
    size_t ob1  = lay((size_t)M_PAD * 1024 * 4);   // pong: f32 GEMM output
    size_t oBt2 = lay((size_t)512 * 512 * 2 * 2);
    size_t oBt6 = lay((size_t)1024 * 512 * 2 * 2);
    size_t oBt7 = lay((size_t)1024 * 1024 * 2 * 2);
    size_t oBt8 = lay((size_t)1024 * 1024 * 2 * 2);
    size_t oew     = lay(N_EDGES * 4);
    size_t odis    = lay(N_NODES * 4);
    size_t oselfn  = lay(N_NODES * 4);
    size_t onormw  = lay(N_EDGES * 4);
    size_t opooled = lay((size_t)N_GRAPHS * 1024 * 4);
    size_t oz      = lay((size_t)N_GRAPHS * 2048 * 4);
    size_t zbeg = off;
    size_t odegf   = lay(N_NODES * 4);
    size_t ocounts = lay(N_NODES * 4);
    size_t ocursor = lay(N_NODES * 4);
    size_t ogcnt   = lay(N_GRAPHS * 4);
    size_t zend = off;
    size_t orowp   = lay((N_NODES + 1) * 4);
    size_t ocolsrc = lay(N_EDGES * 4);
    size_t ogstart = lay(N_GRAPHS * 4);
    size_t need_bytes = off;

    char* base = (ws_size >= need_bytes) ? (char*)d_ws : (char*)g_scratch;

    short* b0 = (short*)(base + ob0);
    float* b1f = (float*)(base + ob1);
    // split pairs (A operands) live in b0; f32 GEMM outputs live in b1
    short* S1h = b0;                       short* S1l = b0 + (size_t)M_PAD * 512;   // emb1 out
    float* S2f = b1f;                      // emb2 out f32 (512-wide)
    short* A6h = b0;                       short* A6l = b0 + (size_t)M_PAD * 512;   // agg6 out
    float* S3f = b1f;                      // conv6 out f32 (1024-wide)
    short* A7h = b0;                       short* A7l = b0 + (size_t)M_PAD * 1024;  // agg7 out
    float* S4f = b1f;                      // conv7 out f32
    short* A8h = b0;                       short* A8l = b0 + (size_t)M_PAD * 1024;  // agg8 out
    float* Y   = b1f;                      // conv8 out f32
    short* Bt2h = (short*)(base + oBt2);   short* Bt2l = Bt2h + (size_t)512 * 512;
    short* Bt6h = (short*)(base + oBt6);   short* Bt6l = Bt6h + (size_t)1024 * 512;
    short* Bt7h = (short*)(base + oBt7);   short* Bt7l = Bt7h + (size_t)1024 * 1024;
    short* Bt8h = (short*)(base + oBt8);   short* Bt8l = Bt8h + (size_t)1024 * 1024;
    float* ew     = (float*)(base + oew);
    float* dis    = (float*)(base + odis);
    float* selfn  = (float*)(base + oselfn);
    float* normw  = (float*)(base + onormw);
    float* pooled = (float*)(base + opooled);
    float* z      = (float*)(base + oz);
    float* degf   = (float*)(base + odegf);
    int*   counts = (int*)(base + ocounts);
    int*   cursor = (int*)(base + ocursor);
    int*   gcnt   = (int*)(base + ogcnt);
    int*   row_ptr= (int*)(base + orowp);
    int*   colsrc = (int*)(base + ocolsrc);
    int*   gstart = (int*)(base + ogstart);

    dim3 blk(256);
    int egrid = (N_EDGES + 255) / 256;
    int ngrid = (N_NODES + 255) / 256;
    int mtiles = M_PAD / 128;   // 391

    int nzero = (int)((zend - zbeg) / 4);
    k_zero<<<(nzero + 255) / 256, blk, 0, stream>>>((int*)(base + zbeg), nzero);

    // edge weights + CSR build
    k_edge_mlp<<<egrid, blk, 0, stream>>>(eattr, ep_w1, ep_b1, ep_w2, ep_b2, ew, N_EDGES);
    k_deg<<<egrid, blk, 0, stream>>>(dst, ew, degf, counts, N_EDGES);
    k_dis<<<ngrid, blk, 0, stream>>>(degf, dis, selfn, N_NODES);
    k_scan<<<1, 1024, 0, stream>>>(counts, row_ptr, N_NODES);
    k_scatter<<<egrid, blk, 0, stream>>>(src, dst, ew, dis, row_ptr, cursor, colsrc, normw, N_EDGES);
    k_gcount<<<ngrid, blk, 0, stream>>>(batch, gcnt, N_NODES);
    k_gscan<<<1, 64, 0, stream>>>(gcnt, gstart);

    // weight split+transpose
    k_wsplit_t<<<dim3(512 / 32, 512 / 32), blk, 0, stream>>>(emb_w2, Bt2h, Bt2l, 512, 512);
    k_wsplit_t<<<dim3(1024 / 32, 512 / 32), blk, 0, stream>>>(c6_w, Bt6h, Bt6l, 512, 1024);
    k_wsplit_t<<<dim3(1024 / 32, 1024 / 32), blk, 0, stream>>>(c7_w, Bt7h, Bt7l, 1024, 1024);
    k_wsplit_t<<<dim3(1024 / 32, 1024 / 32), blk, 0, stream>>>(c8_w, Bt8h, Bt8l, 1024, 1024);

    // emb1 (fp32): S1 = split(relu(x@emb_w1+b1))        [b0 split]
    gemm_tile_split<<<dim3(512 / 128, mtiles), blk, 0, stream>>>(x, emb_w1, emb_b1, S1h, S1l, N_NODES, 40, 512);

    // emb2: S2f = relu(S1@emb_w2+b2) f32                [b1 f32]
    gemm_mf<<<dim3(512 / 128, mtiles), blk, 0, stream>>>(S1h, S1l, Bt2h, Bt2l, emb_b2, S2f,
                                                         N_NODES, 512, 512);

    // conv6 (agg-first): A6 = split(agg(S2f)) [b0]; S3f = relu(A6@c6_w+b6) f32 [b1]
    k_agg_f<512><<<N_NODES, 128, 0, stream>>>(S2f, A6h, A6l, row_ptr, colsrc, normw, selfn);
    gemm_mf<<<dim3(1024 / 128, mtiles), blk, 0, stream>>>(A6h, A6l, Bt6h, Bt6l, c6_b, S3f,
                                                          N_NODES, 512, 1024);

    // conv7: A7 = split(agg(S3f)) [b0]; S4f = relu(A7@c7_w+b7) f32 [b1]
    k_agg_f<1024><<<N_NODES, 256, 0, stream>>>(S3f, A7h, A7l, row_ptr, colsrc, normw, selfn);
    gemm_mf<<<dim3(1024 / 128, mtiles), blk, 0, stream>>>(A7h, A7l, Bt7h, Bt7l, c7_b, S4f,
                                                          N_NODES, 1024, 1024);

    // conv8: A8 = split(agg(S4f)) [b0]; Y = relu(A8@c8_w+b8) f32 [b1]
    k_agg_f<1024><<<N_NODES, 256, 0, stream>>>(S4f, A8h, A8l, row_ptr, colsrc, normw, selfn);
    gemm_mf<<<dim3(1024 / 128, mtiles), blk, 0, stream>>>(A8h, A8l, Bt8h, Bt8l, c8_b, Y,
                                                          N_NODES, 1024, 1024);

    // pool + head
    k_pool<<<N_GRAPHS, blk, 0, stream>>>((const float4*)Y, gstart, gcnt, pooled);
    gemm_small<true><<<dim3((2048 + 255) / 256, N_GRAPHS), blk, 0, stream>>>(pooled, fc1_w, fc1_b, z, 1024, 2048);
    gemm_small<false><<<dim3((345 + 255) / 256, N_GRAPHS), blk, 0, stream>>>(z, head_w, head_b, out, 2048, 345);
}

// Round 9
// 2332.282 us; speedup vs baseline: 1.0705x; 1.0065x over previous
//
#include <hip/hip_runtime.h>
#include <math.h>

#define N_NODES 50000
#define N_EDGES 200000
#define N_GRAPHS 128
#define M_PAD 50048   // N_NODES rounded up to 128

typedef short s16x8 __attribute__((ext_vector_type(8)));
typedef float f32x4 __attribute__((ext_vector_type(4)));

// ---------------- persistent private scratch (allocated at dlopen, NOT in kernel_launch) ----
static void* g_scratch = nullptr;
struct ScratchInit {
    ScratchInit() {
        if (hipMalloc(&g_scratch, (size_t)704 * 1024 * 1024) != hipSuccess) g_scratch = nullptr;
    }
};
static ScratchInit g_scratch_init;

// ---------------- bf16 helpers ----------------
__device__ __forceinline__ unsigned short f2bf_rn(float x) {
    unsigned u = __float_as_uint(x);
    unsigned r = (u + 0x7FFFu + ((u >> 16) & 1u)) >> 16;
    return (unsigned short)r;
}
__device__ __forceinline__ float bf2f(unsigned short h) {
    return __uint_as_float(((unsigned)h) << 16);
}

__device__ __forceinline__ void gl_lds16(const void* g, void* l) {
    __builtin_amdgcn_global_load_lds((const __attribute__((address_space(1))) unsigned int*)g,
                                     (__attribute__((address_space(3))) unsigned int*)l, 16, 0, 0);
}

// ---------------- zero a region ----------------
__global__ void k_zero(int* __restrict__ p, int n) {
    int i = blockIdx.x * 256 + threadIdx.x;
    if (i < n) p[i] = 0;
}

// ---------------- edge-weight MLP ----------------
__global__ void k_edge_mlp(const float* __restrict__ ea, const float* __restrict__ w1,
                           const float* __restrict__ b1, const float* __restrict__ w2,
                           const float* __restrict__ b2, float* __restrict__ ew, int E) {
    int e = blockIdx.x * 256 + threadIdx.x;
    if (e >= E) return;
    float a0 = ea[e * 3 + 0], a1 = ea[e * 3 + 1], a2 = ea[e * 3 + 2];
    float acc = b2[0];
#pragma unroll
    for (int j = 0; j < 64; j++) {
        float h = fmaf(a0, w1[j], fmaf(a1, w1[64 + j], fmaf(a2, w1[128 + j], b1[j])));
        h = fmaxf(h, 0.0f);
        acc = fmaf(h, w2[j], acc);
    }
    ew[e] = 1.0f / (1.0f + expf(-acc));
}

// ---------------- degree + histogram ----------------
__global__ void k_deg(const int* __restrict__ dst, const float* __restrict__ ew,
                      float* __restrict__ degf, int* __restrict__ counts, int E) {
    int e = blockIdx.x * 256 + threadIdx.x;
    if (e >= E) return;
    unsigned d = (unsigned)dst[e];
    if (d >= N_NODES) return;
    atomicAdd(&degf[d], ew[e]);
    atomicAdd(&counts[d], 1);
}

__global__ void k_dis(const float* __restrict__ degf, float* __restrict__ dis,
                      float* __restrict__ selfn, int n) {
    int i = blockIdx.x * 256 + threadIdx.x;
    if (i >= n) return;
    float d = degf[i] + 1.0f;
    float r = (float)(1.0 / sqrt((double)d));
    dis[i] = r;
    selfn[i] = r * r;
}

// ---------------- device-wide scan (3 phases) — replaces the 1-block serial scan ------------
// Phase 1: per-block (1024 elems, 256 thr) inclusive scan -> row_ptr[i+1] (no block offset),
//          block totals -> bsum[b].
__global__ void k_scan1(const int* __restrict__ counts, int* __restrict__ row_ptr,
                        int* __restrict__ bsum, int n) {
    __shared__ int wsum[4];
    int b = blockIdx.x, t = threadIdx.x;
    int base = b * 1024 + t * 4;
    int v0 = 0, v1 = 0, v2 = 0, v3 = 0;
    if (base + 3 < n) {
        int4 c = *(const int4*)(counts + base);
        v0 = c.x; v1 = c.y; v2 = c.z; v3 = c.w;
    } else {
        if (base     < n) v0 = counts[base];
        if (base + 1 < n) v1 = counts[base + 1];
        if (base + 2 < n) v2 = counts[base + 2];
    }
    int tot = v0 + v1 + v2 + v3;
    int lane = t & 63, w = t >> 6;
    int x = tot;
#pragma unroll
    for (int o = 1; o < 64; o <<= 1) {
        int y = __shfl_up(x, o);
        if (lane >= o) x += y;
    }
    if (lane == 63) wsum[w] = x;
    __syncthreads();
    int wo = 0;
    for (int i = 0; i < w; i++) wo += wsum[i];
    int excl = wo + x - tot;
    int i0 = excl + v0, i1 = i0 + v1, i2 = i1 + v2, i3 = i2 + v3;
    if (base     < n) row_ptr[base + 1] = i0;
    if (base + 1 < n) row_ptr[base + 2] = i1;
    if (base + 2 < n) row_ptr[base + 3] = i2;
    if (base + 3 < n) row_ptr[base + 4] = i3;
    if (t == 255) bsum[b] = i3;   // block total (v's are 0 past n)
}

// Phase 2: exclusive scan of block sums (nb <= 64), one wave.
__global__ void k_scan2(int* __restrict__ bsum, int nb) {
    int t = threadIdx.x;
    int orig = (t < nb) ? bsum[t] : 0;
    int v = orig;
#pragma unroll
    for (int o = 1; o < 64; o <<= 1) {
        int y = __shfl_up(v, o);
        if (t >= o) v += y;
    }
    if (t < nb) bsum[t] = v - orig;
}

// Phase 3: add block offsets; set row_ptr[0] = 0.
__global__ void k_scan3(int* __restrict__ row_ptr, const int* __restrict__ bsum, int n) {
    int i = blockIdx.x * 256 + threadIdx.x;
    if (i == 0) row_ptr[0] = 0;
    if (i < n) row_ptr[i + 1] += bsum[i >> 10];
}

// ---------------- CSR scatter ----------------
__global__ void k_scatter(const int* __restrict__ src, const int* __restrict__ dst,
                          const float* __restrict__ ew, const float* __restrict__ dis,
                          const int* __restrict__ row_ptr, int* __restrict__ cursor,
                          int* __restrict__ colsrc, float* __restrict__ normw, int E) {
    int e = blockIdx.x * 256 + threadIdx.x;
    if (e >= E) return;
    unsigned d = (unsigned)dst[e], s = (unsigned)src[e];
    if (d >= N_NODES || s >= N_NODES) return;
    int pos = row_ptr[d] + atomicAdd(&cursor[d], 1);
    if ((unsigned)pos >= N_EDGES) return;
    colsrc[pos] = (int)s;
    normw[pos] = dis[s] * ew[e] * dis[d];
}

// ---------------- per-graph counts ----------------
__global__ void k_gcount(const int* __restrict__ batch, int* __restrict__ gcnt, int n) {
    int i = blockIdx.x * 256 + threadIdx.x;
    if (i >= n) return;
    unsigned b = (unsigned)batch[i];
    if (b < N_GRAPHS) atomicAdd(&gcnt[b], 1);
}

__global__ void k_gscan(const int* __restrict__ gcnt, int* __restrict__ gstart) {
    if (threadIdx.x == 0 && blockIdx.x == 0) {
        int s = 0;
        for (int g = 0; g < N_GRAPHS; g++) { gstart[g] = s; s += gcnt[g]; }
    }
}

// ---------------- weight split+transpose: W[K][N] f32 -> Bt_hi/Bt_lo[N][K] bf16 ----------------
__global__ void k_wsplit_t(const float* __restrict__ W, short* __restrict__ Bth,
                           short* __restrict__ Btl, int K, int N) {
    __shared__ float t[32][33];
    int tx = threadIdx.x % 32, ty = threadIdx.x / 32;   // 32 x 8
    int bx = blockIdx.x, by = blockIdx.y;
#pragma unroll
    for (int i = 0; i < 4; i++) {
        int k = by * 32 + ty + i * 8;
        t[ty + i * 8][tx] = W[(size_t)k * N + bx * 32 + tx];
    }
    __syncthreads();
#pragma unroll
    for (int i = 0; i < 4; i++) {
        int n = bx * 32 + ty + i * 8;
        int k = by * 32 + tx;
        float v = t[tx][ty + i * 8];
        unsigned short h = f2bf_rn(v);
        Bth[(size_t)n * K + k] = (short)h;
        Btl[(size_t)n * K + k] = (short)f2bf_rn(v - bf2f(h));
    }
}

// ---------------- fp32 tiled GEMM (emb1), epilogue writes split bf16 ----------------
__launch_bounds__(256)
__global__ void gemm_tile_split(const float* __restrict__ A, const float* __restrict__ B,
                                const float* __restrict__ bias, short* __restrict__ Chi,
                                short* __restrict__ Clo, int M, int K, int N) {
    constexpr int BM = 128, BN = 128, BK = 8, TM = 8, TN = 8;
    __shared__ float As[BK * BM];
    __shared__ float Bs[BK * BN];
    int tid = threadIdx.x;
    int tx = tid % (BN / TN);
    int ty = tid / (BN / TN);
    int m0 = blockIdx.y * BM, n0 = blockIdx.x * BN;
    float acc[TM][TN] = {};
    int arow = tid / 2;
    int acol = (tid % 2) * 4;
    int brow = tid / 32;
    int bcol = (tid % 32) * 4;
    for (int k0 = 0; k0 < K; k0 += BK) {
        float4 av = make_float4(0.f, 0.f, 0.f, 0.f);
        int gr = m0 + arow;
        if (gr < M) av = *(const float4*)(A + (size_t)gr * K + k0 + acol);
        As[(acol + 0) * BM + arow] = av.x;
        As[(acol + 1) * BM + arow] = av.y;
        As[(acol + 2) * BM + arow] = av.z;
        As[(acol + 3) * BM + arow] = av.w;
        float4 bv = *(const float4*)(B + (size_t)(k0 + brow) * N + n0 + bcol);
        *(float4*)(Bs + brow * BN + bcol) = bv;
        __syncthreads();
#pragma unroll
        for (int kk = 0; kk < BK; kk++) {
            float a[TM], b[TN];
#pragma unroll
            for (int i = 0; i < TM; i += 4)
                *(float4*)(a + i) = *(const float4*)(As + kk * BM + ty * TM + i);
#pragma unroll
            for (int j = 0; j < TN; j += 4)
                *(float4*)(b + j) = *(const float4*)(Bs + kk * BN + tx * TN + j);
#pragma unroll
            for (int i = 0; i < TM; i++)
#pragma unroll
                for (int j = 0; j < TN; j++)
                    acc[i][j] = fmaf(a[i], b[j], acc[i][j]);
        }
        __syncthreads();
    }
#pragma unroll
    for (int i = 0; i < TM; i++) {
        int r = m0 + ty * TM + i;
        if (r >= M) continue;
#pragma unroll
        for (int j = 0; j < TN; j += 4) {
            int c = n0 + tx * TN + j;
            short4 hv, lv;
            float vv[4];
#pragma unroll
            for (int q = 0; q < 4; q++) {
                float v = acc[i][j + q] + bias[c + q];
                vv[q] = fmaxf(v, 0.f);
            }
            hv.x = (short)f2bf_rn(vv[0]); hv.y = (short)f2bf_rn(vv[1]);
            hv.z = (short)f2bf_rn(vv[2]); hv.w = (short)f2bf_rn(vv[3]);
            lv.x = (short)f2bf_rn(vv[0] - bf2f(hv.x));
            lv.y = (short)f2bf_rn(vv[1] - bf2f(hv.y));
            lv.z = (short)f2bf_rn(vv[2] - bf2f(hv.z));
            lv.w = (short)f2bf_rn(vv[3] - bf2f(hv.w));
            *(short4*)(Chi + (size_t)r * N + c) = hv;
            *(short4*)(Clo + (size_t)r * N + c) = lv;
        }
    }
}

// ---------------- bf16x3 MFMA GEMM, 128x128 tile, 256 threads -------------------------------
// A (M_PAD x K) hi/lo bf16, B^T (N x K) hi/lo bf16.  C = relu(A@B + bias) as f32.
// f32 dword-store epilogue is the proven-fast variant (r3/r8); split epilogue cost +100us.
__launch_bounds__(256)
__global__ void gemm_mf(const short* __restrict__ Ah, const short* __restrict__ Al,
                        const short* __restrict__ Bh, const short* __restrict__ Bl,
                        const float* __restrict__ bias, float* __restrict__ C,
                        int M, int K, int N) {
    __shared__ short lds[4 * 4096];           // 32 KB
    short* lA_h = lds;
    short* lA_l = lds + 4096;
    short* lB_h = lds + 8192;
    short* lB_l = lds + 12288;
    int tid = threadIdx.x, lane = tid & 63, wave = tid >> 6;
    int wm = wave >> 1, wn = wave & 1;
    int q4 = lane >> 4, l15 = lane & 15;
    int m0 = blockIdx.y * 128, n0 = blockIdx.x * 128;

    f32x4 acc[4][4] = {};

    for (int k0 = 0; k0 < K; k0 += 32) {
        __syncthreads();
#pragma unroll
        for (int it = 0; it < 8; ++it) {
            int arr = it >> 1;
            int ca = ((it & 1) << 8) + tid;          // chunk within array, 0..511
            int r = ca >> 2, slot = ca & 3;
            int q = slot ^ ((r >> 1) & 3);           // xor-swizzle: conflict-free frag reads
            int grow = (arr < 2) ? (m0 + r) : (n0 + r);
            const short* gb = (arr == 0) ? Ah : (arr == 1) ? Al : (arr == 2) ? Bh : Bl;
            const short* g = gb + (size_t)grow * K + k0 + q * 8;
            int chunk_base = ((it & 1) << 8) + (wave << 6);   // wave-uniform
            short* l = lds + arr * 4096 + chunk_base * 8;
            gl_lds16(g, l);
        }
        __syncthreads();
        s16x8 a_h[4], a_l[4], b_h[4], b_l[4];
#pragma unroll
        for (int t = 0; t < 4; ++t) {
            int rA = wm * 64 + t * 16 + l15;
            int pA = rA * 4 + (q4 ^ ((rA >> 1) & 3));
            a_h[t] = *(const s16x8*)(lA_h + pA * 8);
            a_l[t] = *(const s16x8*)(lA_l + pA * 8);
            int rB = wn * 64 + t * 16 + l15;
            int pB = rB * 4 + (q4 ^ ((rB >> 1) & 3));
            b_h[t] = *(const s16x8*)(lB_h + pB * 8);
            b_l[t] = *(const s16x8*)(lB_l + pB * 8);
        }
#pragma unroll
        for (int tm = 0; tm < 4; ++tm)
#pragma unroll
            for (int tn = 0; tn < 4; ++tn) {
                acc[tm][tn] = __builtin_amdgcn_mfma_f32_16x16x32_bf16(a_h[tm], b_h[tn], acc[tm][tn], 0, 0, 0);
                acc[tm][tn] = __builtin_amdgcn_mfma_f32_16x16x32_bf16(a_h[tm], b_l[tn], acc[tm][tn], 0, 0, 0);
                acc[tm][tn] = __builtin_amdgcn_mfma_f32_16x16x32_bf16(a_l[tm], b_h[tn], acc[tm][tn], 0, 0, 0);
            }
    }
    // epilogue: C/D layout col=lane&15, row=(lane>>4)*4+reg
#pragma unroll
    for (int tm = 0; tm < 4; ++tm) {
#pragma unroll
        for (int tn = 0; tn < 4; ++tn) {
            int col = n0 + wn * 64 + tn * 16 + l15;
#pragma unroll
            for (int r = 0; r < 4; ++r) {
                int row = m0 + wm * 64 + tm * 16 + q4 * 4 + r;
                if (row < M) {
                    float v = acc[tm][tn][r] + bias[col];
                    C[(size_t)row * N + col] = fmaxf(v, 0.f);
                }
            }
        }
    }
}

// ---------------- CSR aggregation: f32 in -> split bf16 out, 2-way unrolled edge loop ------
// out[i] = selfn[i]*x[i] + sum_e w_e*x[src_e].  Two independent gathers in flight per
// iteration (dual accumulators) to halve exposed load latency.
template <int F>
__global__ void k_agg_f(const float* __restrict__ in, short* __restrict__ out_hi,
                        short* __restrict__ out_lo, const int* __restrict__ row_ptr,
                        const int* __restrict__ colsrc, const float* __restrict__ normw,
                        const float* __restrict__ selfn) {
    int i = blockIdx.x;
    int t = threadIdx.x;
    size_t o = (size_t)i * F + t * 4;
    float4 v = *(const float4*)(in + o);
    float sn = selfn[i];
    float a0 = sn * v.x, a1 = sn * v.y, a2 = sn * v.z, a3 = sn * v.w;
    float c0 = 0.f, c1 = 0.f, c2 = 0.f, c3 = 0.f;
    int e = row_ptr[i], eend = row_ptr[i + 1];
    for (; e + 1 < eend; e += 2) {
        unsigned s0 = (unsigned)colsrc[e];
        unsigned s1 = (unsigned)colsrc[e + 1];
        float w0 = normw[e], w1 = normw[e + 1];
        float4 u0 = make_float4(0.f, 0.f, 0.f, 0.f);
        float4 u1 = make_float4(0.f, 0.f, 0.f, 0.f);
        if (s0 < N_NODES) u0 = *(const float4*)(in + (size_t)s0 * F + t * 4);
        if (s1 < N_NODES) u1 = *(const float4*)(in + (size_t)s1 * F + t * 4);
        a0 = fmaf(w0, u0.x, a0); a1 = fmaf(w0, u0.y, a1);
        a2 = fmaf(w0, u0.z, a2); a3 = fmaf(w0, u0.w, a3);
        c0 = fmaf(w1, u1.x, c0); c1 = fmaf(w1, u1.y, c1);
        c2 = fmaf(w1, u1.z, c2); c3 = fmaf(w1, u1.w, c3);
    }
    if (e < eend) {
        unsigned s = (unsigned)colsrc[e];
        float w = normw[e];
        if (s < N_NODES) {
            float4 u = *(const float4*)(in + (size_t)s * F + t * 4);
            a0 = fmaf(w, u.x, a0); a1 = fmaf(w, u.y, a1);
            a2 = fmaf(w, u.z, a2); a3 = fmaf(w, u.w, a3);
        }
    }
    a0 += c0; a1 += c1; a2 += c2; a3 += c3;
    short4 hv, lv;
    hv.x = (short)f2bf_rn(a0); hv.y = (short)f2bf_rn(a1);
    hv.z = (short)f2bf_rn(a2); hv.w = (short)f2bf_rn(a3);
    lv.x = (short)f2bf_rn(a0 - bf2f((unsigned short)hv.x));
    lv.y = (short)f2bf_rn(a1 - bf2f((unsigned short)hv.y));
    lv.z = (short)f2bf_rn(a2 - bf2f((unsigned short)hv.z));
    lv.w = (short)f2bf_rn(a3 - bf2f((unsigned short)hv.w));
    *(short4*)(out_hi + o) = hv;
    *(short4*)(out_lo + o) = lv;
}

// ---------------- mean-pool (double accumulation) ----------------
__global__ void k_pool(const float4* __restrict__ h, const int* __restrict__ gstart,
                       const int* __restrict__ gcnt, float* __restrict__ pooled) {
    int g = blockIdx.x;
    int t = threadIdx.x;
    int beg = gstart[g], cnt = gcnt[g];
    if (beg + cnt > N_NODES) cnt = N_NODES - beg;
    double a0 = 0, a1 = 0, a2 = 0, a3 = 0;
    for (int n = 0; n < cnt; n++) {
        float4 v = h[(size_t)(beg + n) * 256 + t];
        a0 += v.x; a1 += v.y; a2 += v.z; a3 += v.w;
    }
    float inv = 1.0f / fmaxf((float)gcnt[g], 1.0f);
    pooled[g * 1024 + t * 4 + 0] = (float)a0 * inv;
    pooled[g * 1024 + t * 4 + 1] = (float)a1 * inv;
    pooled[g * 1024 + t * 4 + 2] = (float)a2 * inv;
    pooled[g * 1024 + t * 4 + 3] = (float)a3 * inv;
}

// ---------------- small GEMM (M=128), double accumulation ----------------
template <bool RELU>
__global__ void gemm_small(const float* __restrict__ A, const float* __restrict__ B,
                           const float* __restrict__ bias, float* __restrict__ C,
                           int K, int N) {
    int n = blockIdx.x * 256 + threadIdx.x;
    int m = blockIdx.y;
    if (n >= N) return;
    const float* a = A + (size_t)m * K;
    double acc = 0.0;
    for (int k = 0; k < K; k += 4) {
        acc += (double)a[k] * (double)B[(size_t)k * N + n];
        acc += (double)a[k + 1] * (double)B[(size_t)(k + 1) * N + n];
        acc += (double)a[k + 2] * (double)B[(size_t)(k + 2) * N + n];
        acc += (double)a[k + 3] * (double)B[(size_t)(k + 3) * N + n];
    }
    float r = (float)acc + bias[n];
    if (RELU) r = fmaxf(r, 0.0f);
    C[(size_t)m * N + n] = r;
}

extern "C" void kernel_launch(void* const* d_in, const int* in_sizes, int n_in,
                              void* d_out, int out_size, void* d_ws, size_t ws_size,
                              hipStream_t stream) {
    const float* x      = (const float*)d_in[0];
    const float* eattr  = (const float*)d_in[1];
    const int*   eidx   = (const int*)d_in[2];
    const int*   batch  = (const int*)d_in[3];
    const float* emb_w1 = (const float*)d_in[4];
    const float* emb_b1 = (const float*)d_in[5];
    const float* emb_w2 = (const float*)d_in[6];
    const float* emb_b2 = (const float*)d_in[7];
    const float* ep_w1  = (const float*)d_in[8];
    const float* ep_b1  = (const float*)d_in[9];
    const float* ep_w2  = (const float*)d_in[10];
    const float* ep_b2  = (const float*)d_in[11];
    const float* c6_w   = (const float*)d_in[12];
    const float* c6_b   = (const float*)d_in[13];
    const float* c7_w   = (const float*)d_in[14];
    const float* c7_b   = (const float*)d_in[15];
    const float* c8_w   = (const float*)d_in[16];
    const float* c8_b   = (const float*)d_in[17];
    const float* fc1_w  = (const float*)d_in[18];
    const float* fc1_b  = (const float*)d_in[19];
    const float* head_w = (const float*)d_in[20];
    const float* head_b = (const float*)d_in[21];
    float* out = (float*)d_out;

    const int* src = eidx;
    const int* dst = eidx + N_EDGES;

    // ---- workspace layout (bytes) ----
    size_t off = 0;
    auto lay = [&](size_t nbytes) -> size_t {
        size_t p = off;
        off += (nbytes + 255) & ~(size_t)255;
        return p;
    };
    size_t ob0  = lay((size_t)M_PAD * 1024 * 4);   // ping: split pair (hi|lo)
    size_t ob1  = lay((size_t)M_PAD * 1024 * 4);   // pong: f32 GEMM output
    size_t oBt2 = lay((size_t)512 * 512 * 2 * 2);
    size_t oBt6 = lay((size_t)1024 * 512 * 2 * 2);
    size_t oBt7 = lay((size_t)1024 * 1024 * 2 * 2);
    size_t oBt8 = lay((size_t)1024 * 1024 * 2 * 2);
    size_t oew     = lay(N_EDGES * 4);
    size_t odis    = lay(N_NODES * 4);
    size_t oselfn  = lay(N_NODES * 4);
    size_t onormw  = lay(N_EDGES * 4);
    size_t opooled = lay((size_t)N_GRAPHS * 1024 * 4);
    size_t oz      = lay((size_t)N_GRAPHS * 2048 * 4);
    size_t zbeg = off;
    size_t odegf   = lay(N_NODES * 4);
    size_t ocounts = lay(N_NODES * 4);
    size_t ocursor = lay(N_NODES * 4);
    size_t ogcnt   = lay(N_GRAPHS * 4);
    size_t zend = off;
    size_t orowp   = lay((N_NODES + 1) * 4);
    size_t ocolsrc = lay(N_EDGES * 4);
    size_t ogstart = lay(N_GRAPHS * 4);
    size_t obsum   = lay(64 * 4);
    size_t need_bytes = off;

    char* base = (ws_size >= need_bytes) ? (char*)d_ws : (char*)g_scratch;

    short* b0 = (short*)(base + ob0);
    float* b1f = (float*)(base + ob1);
    // split pairs (A operands) live in b0; f32 GEMM outputs live in b1
    short* S1h = b0;                       short* S1l = b0 + (size_t)M_PAD * 512;   // emb1 out
    float* S2f = b1f;                      // emb2 out f32 (512-wide)
    short* A6h = b0;                       short* A6l = b0 + (size_t)M_PAD * 512;   // agg6 out
    float* S3f = b1f;                      // conv6 out f32 (1024-wide)
    short* A7h = b0;                       short* A7l = b0 + (size_t)M_PAD * 1024;  // agg7 out
    float* S4f = b1f;                      // conv7 out f32
    short* A8h = b0;                       short* A8l = b0 + (size_t)M_PAD * 1024;  // agg8 out
    float* Y   = b1f;                      // conv8 out f32
    short* Bt2h = (short*)(base + oBt2);   short* Bt2l = Bt2h + (size_t)512 * 512;
    short* Bt6h = (short*)(base + oBt6);   short* Bt6l = Bt6h + (size_t)1024 * 512;
    short* Bt7h = (short*)(base + oBt7);   short* Bt7l = Bt7h + (size_t)1024 * 1024;
    short* Bt8h = (short*)(base + oBt8);   short* Bt8l = Bt8h + (size_t)1024 * 1024;
    float* ew     = (float*)(base + oew);
    float* dis    = (float*)(base + odis);
    float* selfn  = (float*)(base + oselfn);
    float* normw  = (float*)(base + onormw);
    float* pooled = (float*)(base + opooled);
    float* z      = (float*)(base + oz);
    float* degf   = (float*)(base + odegf);
    int*   counts = (int*)(base + ocounts);
    int*   cursor = (int*)(base + ocursor);
    int*   gcnt   = (int*)(base + ogcnt);
    int*   row_ptr= (int*)(base + orowp);
    int*   colsrc = (int*)(base + ocolsrc);
    int*   gstart = (int*)(base + ogstart);
    int*   bsum   = (int*)(base + obsum);

    dim3 blk(256);
    int egrid = (N_EDGES + 255) / 256;
    int ngrid = (N_NODES + 255) / 256;
    int mtiles = M_PAD / 128;   // 391
    int nb = (N_NODES + 1023) / 1024;   // 49 scan blocks

    int nzero = (int)((zend - zbeg) / 4);
    k_zero<<<(nzero + 255) / 256, blk, 0, stream>>>((int*)(base + zbeg), nzero);

    // edge weights + CSR build (multi-block scan)
    k_edge_mlp<<<egrid, blk, 0, stream>>>(eattr, ep_w1, ep_b1, ep_w2, ep_b2, ew, N_EDGES);
    k_deg<<<egrid, blk, 0, stream>>>(dst, ew, degf, counts, N_EDGES);
    k_dis<<<ngrid, blk, 0, stream>>>(degf, dis, selfn, N_NODES);
    k_scan1<<<nb, blk, 0, stream>>>(counts, row_ptr, bsum, N_NODES);
    k_scan2<<<1, 64, 0, stream>>>(bsum, nb);
    k_scan3<<<ngrid, blk, 0, stream>>>(row_ptr, bsum, N_NODES);
    k_scatter<<<egrid, blk, 0, stream>>>(src, dst, ew, dis, row_ptr, cursor, colsrc, normw, N_EDGES);
    k_gcount<<<ngrid, blk, 0, stream>>>(batch, gcnt, N_NODES);
    k_gscan<<<1, 64, 0, stream>>>(gcnt, gstart);

    // weight split+transpose
    k_wsplit_t<<<dim3(512 / 32, 512 / 32), blk, 0, stream>>>(emb_w2, Bt2h, Bt2l, 512, 512);
    k_wsplit_t<<<dim3(1024 / 32, 512 / 32), blk, 0, stream>>>(c6_w, Bt6h, Bt6l, 512, 1024);
    k_wsplit_t<<<dim3(1024 / 32, 1024 / 32), blk, 0, stream>>>(c7_w, Bt7h, Bt7l, 1024, 1024);
    k_wsplit_t<<<dim3(1024 / 32, 1024 / 32), blk, 0, stream>>>(c8_w, Bt8h, Bt8l, 1024, 1024);

    // emb1 (fp32): S1 = split(relu(x@emb_w1+b1))        [b0 split]
    gemm_tile_split<<<dim3(512 / 128, mtiles), blk, 0, stream>>>(x, emb_w1, emb_b1, S1h, S1l, N_NODES, 40, 512);

    // emb2: S2f = relu(S1@emb_w2+b2) f32                [b1 f32]
    gemm_mf<<<dim3(512 / 128, mtiles), blk, 0, stream>>>(S1h, S1l, Bt2h, Bt2l, emb_b2, S2f,
                                                         N_NODES, 512, 512);

    // conv6 (agg-first): A6 = split(agg(S2f)) [b0]; S3f = relu(A6@c6_w+b6) f32 [b1]
    k_agg_f<512><<<N_NODES, 128, 0, stream>>>(S2f, A6h, A6l, row_ptr, colsrc, normw, selfn);
    gemm_mf<<<dim3(1024 / 128, mtiles), blk, 0, stream>>>(A6h, A6l, Bt6h, Bt6l, c6_b, S3f,
                                                          N_NODES, 512, 1024);

    // conv7: A7 = split(agg(S3f)) [b0]; S4f = relu(A7@c7_w+b7) f32 [b1]
    k_agg_f<1024><<<N_NODES, 256, 0, stream>>>(S3f, A7h, A7l, row_ptr, colsrc, normw, selfn);
    gemm_mf<<<dim3(1024 / 128, mtiles), blk, 0, stream>>>(A7h, A7l, Bt7h, Bt7l, c7_b, S4f,
                                                          N_NODES, 1024, 1024);

    // conv8: A8 = split(agg(S4f)) [b0]; Y = relu(A8@c8_w+b8) f32 [b1]
    k_agg_f<1024><<<N_NODES, 256, 0, stream>>>(S4f, A8h, A8l, row_ptr, colsrc, normw, selfn);
    gemm_mf<<<dim3(1024 / 128, mtiles), blk, 0, stream>>>(A8h, A8l, Bt8h, Bt8l, c8_b, Y,
                                                          N_NODES, 1024, 1024);

    // pool + head
    k_pool<<<N_GRAPHS, blk, 0, stream>>>((const float4*)Y, gstart, gcnt, pooled);
    gemm_small<true><<<dim3((2048 + 255) / 256, N_GRAPHS), blk, 0, stream>>>(pooled, fc1_w, fc1_b, z, 1024, 2048);
    gemm_small<false><<<dim3((345 + 255) / 256, N_GRAPHS), blk, 0, stream>>>(z, head_w, head_b, out, 2048, 345);
}

// Round 10
// 1991.857 us; speedup vs baseline: 1.2535x; 1.1709x over previous
//
#include <hip/hip_runtime.h>
#include <math.h>

#define N_NODES 50000
#define N_EDGES 200000
#define N_GRAPHS 128
#define M_PAD 50048   // N_NODES rounded up to 128

typedef short s16x8 __attribute__((ext_vector_type(8)));
typedef float f32x4 __attribute__((ext_vector_type(4)));

// ---------------- persistent private scratch (allocated at dlopen, NOT in kernel_launch) ----
static void* g_scratch = nullptr;
struct ScratchInit {
    ScratchInit() {
        if (hipMalloc(&g_scratch, (size_t)704 * 1024 * 1024) != hipSuccess) g_scratch = nullptr;
    }
};
static ScratchInit g_scratch_init;

// ---------------- bf16 helpers ----------------
__device__ __forceinline__ unsigned short f2bf_rn(float x) {
    unsigned u = __float_as_uint(x);
    unsigned r = (u + 0x7FFFu + ((u >> 16) & 1u)) >> 16;
    return (unsigned short)r;
}
__device__ __forceinline__ float bf2f(unsigned short h) {
    return __uint_as_float(((unsigned)h) << 16);
}

__device__ __forceinline__ void gl_lds16(const void* g, void* l) {
    __builtin_amdgcn_global_load_lds((const __attribute__((address_space(1))) unsigned int*)g,
                                     (__attribute__((address_space(3))) unsigned int*)l, 16, 0, 0);
}

// ---------------- zero a region ----------------
__global__ void k_zero(int* __restrict__ p, int n) {
    int i = blockIdx.x * 256 + threadIdx.x;
    if (i < n) p[i] = 0;
}

// ---------------- edge-weight MLP ----------------
__global__ void k_edge_mlp(const float* __restrict__ ea, const float* __restrict__ w1,
                           const float* __restrict__ b1, const float* __restrict__ w2,
                           const float* __restrict__ b2, float* __restrict__ ew, int E) {
    int e = blockIdx.x * 256 + threadIdx.x;
    if (e >= E) return;
    float a0 = ea[e * 3 + 0], a1 = ea[e * 3 + 1], a2 = ea[e * 3 + 2];
    float acc = b2[0];
#pragma unroll
    for (int j = 0; j < 64; j++) {
        float h = fmaf(a0, w1[j], fmaf(a1, w1[64 + j], fmaf(a2, w1[128 + j], b1[j])));
        h = fmaxf(h, 0.0f);
        acc = fmaf(h, w2[j], acc);
    }
    ew[e] = 1.0f / (1.0f + expf(-acc));
}

// ---------------- degree + histogram ----------------
__global__ void k_deg(const int* __restrict__ dst, const float* __restrict__ ew,
                      float* __restrict__ degf, int* __restrict__ counts, int E) {
    int e = blockIdx.x * 256 + threadIdx.x;
    if (e >= E) return;
    unsigned d = (unsigned)dst[e];
    if (d >= N_NODES) return;
    atomicAdd(&degf[d], ew[e]);
    atomicAdd(&counts[d], 1);
}

__global__ void k_dis(const float* __restrict__ degf, float* __restrict__ dis,
                      float* __restrict__ selfn, int n) {
    int i = blockIdx.x * 256 + threadIdx.x;
    if (i >= n) return;
    float d = degf[i] + 1.0f;
    float r = (float)(1.0 / sqrt((double)d));
    dis[i] = r;
    selfn[i] = r * r;
}

// ---------------- device-wide scan (3 phases) ----------------
__global__ void k_scan1(const int* __restrict__ counts, int* __restrict__ row_ptr,
                        int* __restrict__ bsum, int n) {
    __shared__ int wsum[4];
    int b = blockIdx.x, t = threadIdx.x;
    int base = b * 1024 + t * 4;
    int v0 = 0, v1 = 0, v2 = 0, v3 = 0;
    if (base + 3 < n) {
        int4 c = *(const int4*)(counts + base);
        v0 = c.x; v1 = c.y; v2 = c.z; v3 = c.w;
    } else {
        if (base     < n) v0 = counts[base];
        if (base + 1 < n) v1 = counts[base + 1];
        if (base + 2 < n) v2 = counts[base + 2];
    }
    int tot = v0 + v1 + v2 + v3;
    int lane = t & 63, w = t >> 6;
    int x = tot;
#pragma unroll
    for (int o = 1; o < 64; o <<= 1) {
        int y = __shfl_up(x, o);
        if (lane >= o) x += y;
    }
    if (lane == 63) wsum[w] = x;
    __syncthreads();
    int wo = 0;
    for (int i = 0; i < w; i++) wo += wsum[i];
    int excl = wo + x - tot;
    int i0 = excl + v0, i1 = i0 + v1, i2 = i1 + v2, i3 = i2 + v3;
    if (base     < n) row_ptr[base + 1] = i0;
    if (base + 1 < n) row_ptr[base + 2] = i1;
    if (base + 2 < n) row_ptr[base + 3] = i2;
    if (base + 3 < n) row_ptr[base + 4] = i3;
    if (t == 255) bsum[b] = i3;
}

__global__ void k_scan2(int* __restrict__ bsum, int nb) {
    int t = threadIdx.x;
    int orig = (t < nb) ? bsum[t] : 0;
    int v = orig;
#pragma unroll
    for (int o = 1; o < 64; o <<= 1) {
        int y = __shfl_up(v, o);
        if (t >= o) v += y;
    }
    if (t < nb) bsum[t] = v - orig;
}

__global__ void k_scan3(int* __restrict__ row_ptr, const int* __restrict__ bsum, int n) {
    int i = blockIdx.x * 256 + threadIdx.x;
    if (i == 0) row_ptr[0] = 0;
    if (i < n) row_ptr[i + 1] += bsum[i >> 10];
}

// ---------------- CSR scatter ----------------
__global__ void k_scatter(const int* __restrict__ src, const int* __restrict__ dst,
                          const float* __restrict__ ew, const float* __restrict__ dis,
                          const int* __restrict__ row_ptr, int* __restrict__ cursor,
                          int* __restrict__ colsrc, float* __restrict__ normw, int E) {
    int e = blockIdx.x * 256 + threadIdx.x;
    if (e >= E) return;
    unsigned d = (unsigned)dst[e], s = (unsigned)src[e];
    if (d >= N_NODES || s >= N_NODES) return;
    int pos = row_ptr[d] + atomicAdd(&cursor[d], 1);
    if ((unsigned)pos >= N_EDGES) return;
    colsrc[pos] = (int)s;
    normw[pos] = dis[s] * ew[e] * dis[d];
}

// ---------------- per-graph counts ----------------
__global__ void k_gcount(const int* __restrict__ batch, int* __restrict__ gcnt, int n) {
    int i = blockIdx.x * 256 + threadIdx.x;
    if (i >= n) return;
    unsigned b = (unsigned)batch[i];
    if (b < N_GRAPHS) atomicAdd(&gcnt[b], 1);
}

__global__ void k_gscan(const int* __restrict__ gcnt, int* __restrict__ gstart) {
    if (threadIdx.x == 0 && blockIdx.x == 0) {
        int s = 0;
        for (int g = 0; g < N_GRAPHS; g++) { gstart[g] = s; s += gcnt[g]; }
    }
}

// ---------------- weight split+transpose: W[K][N] f32 -> Bt_hi/Bt_lo[N][K] bf16 ----------------
__global__ void k_wsplit_t(const float* __restrict__ W, short* __restrict__ Bth,
                           short* __restrict__ Btl, int K, int N) {
    __shared__ float t[32][33];
    int tx = threadIdx.x % 32, ty = threadIdx.x / 32;   // 32 x 8
    int bx = blockIdx.x, by = blockIdx.y;
#pragma unroll
    for (int i = 0; i < 4; i++) {
        int k = by * 32 + ty + i * 8;
        t[ty + i * 8][tx] = W[(size_t)k * N + bx * 32 + tx];
    }
    __syncthreads();
#pragma unroll
    for (int i = 0; i < 4; i++) {
        int n = bx * 32 + ty + i * 8;
        int k = by * 32 + tx;
        float v = t[tx][ty + i * 8];
        unsigned short h = f2bf_rn(v);
        Bth[(size_t)n * K + k] = (short)h;
        Btl[(size_t)n * K + k] = (short)f2bf_rn(v - bf2f(h));
    }
}

// ---------------- fp32 tiled GEMM (emb1), epilogue writes split bf16 ----------------
__launch_bounds__(256)
__global__ void gemm_tile_split(const float* __restrict__ A, const float* __restrict__ B,
                                const float* __restrict__ bias, short* __restrict__ Chi,
                                short* __restrict__ Clo, int M, int K, int N) {
    constexpr int BM = 128, BN = 128, BK = 8, TM = 8, TN = 8;
    __shared__ float As[BK * BM];
    __shared__ float Bs[BK * BN];
    int tid = threadIdx.x;
    int tx = tid % (BN / TN);
    int ty = tid / (BN / TN);
    int m0 = blockIdx.y * BM, n0 = blockIdx.x * BN;
    float acc[TM][TN] = {};
    int arow = tid / 2;
    int acol = (tid % 2) * 4;
    int brow = tid / 32;
    int bcol = (tid % 32) * 4;
    for (int k0 = 0; k0 < K; k0 += BK) {
        float4 av = make_float4(0.f, 0.f, 0.f, 0.f);
        int gr = m0 + arow;
        if (gr < M) av = *(const float4*)(A + (size_t)gr * K + k0 + acol);
        As[(acol + 0) * BM + arow] = av.x;
        As[(acol + 1) * BM + arow] = av.y;
        As[(acol + 2) * BM + arow] = av.z;
        As[(acol + 3) * BM + arow] = av.w;
        float4 bv = *(const float4*)(B + (size_t)(k0 + brow) * N + n0 + bcol);
        *(float4*)(Bs + brow * BN + bcol) = bv;
        __syncthreads();
#pragma unroll
        for (int kk = 0; kk < BK; kk++) {
            float a[TM], b[TN];
#pragma unroll
            for (int i = 0; i < TM; i += 4)
                *(float4*)(a + i) = *(const float4*)(As + kk * BM + ty * TM + i);
#pragma unroll
            for (int j = 0; j < TN; j += 4)
                *(float4*)(b + j) = *(const float4*)(Bs + kk * BN + tx * TN + j);
#pragma unroll
            for (int i = 0; i < TM; i++)
#pragma unroll
                for (int j = 0; j < TN; j++)
                    acc[i][j] = fmaf(a[i], b[j], acc[i][j]);
        }
        __syncthreads();
    }
#pragma unroll
    for (int i = 0; i < TM; i++) {
        int r = m0 + ty * TM + i;
        if (r >= M) continue;
#pragma unroll
        for (int j = 0; j < TN; j += 4) {
            int c = n0 + tx * TN + j;
            short4 hv, lv;
            float vv[4];
#pragma unroll
            for (int q = 0; q < 4; q++) {
                float v = acc[i][j + q] + bias[c + q];
                vv[q] = fmaxf(v, 0.f);
            }
            hv.x = (short)f2bf_rn(vv[0]); hv.y = (short)f2bf_rn(vv[1]);
            hv.z = (short)f2bf_rn(vv[2]); hv.w = (short)f2bf_rn(vv[3]);
            lv.x = (short)f2bf_rn(vv[0] - bf2f(hv.x));
            lv.y = (short)f2bf_rn(vv[1] - bf2f(hv.y));
            lv.z = (short)f2bf_rn(vv[2] - bf2f(hv.z));
            lv.w = (short)f2bf_rn(vv[3] - bf2f(hv.w));
            *(short4*)(Chi + (size_t)r * N + c) = hv;
            *(short4*)(Clo + (size_t)r * N + c) = lv;
        }
    }
}

// ---------------- bf16x3 MFMA GEMM, 128x128 tile, 256 threads -------------------------------
// A (M_PAD x K) hi/lo bf16, B^T (N x K) hi/lo bf16.  C = relu(A@B + bias) as f32.
// f32 dword-store epilogue is the proven-fast variant (r3/r8); split epilogue cost +100us.
__launch_bounds__(256)
__global__ void gemm_mf(const short* __restrict__ Ah, const short* __restrict__ Al,
                        const short* __restrict__ Bh, const short* __restrict__ Bl,
                        const float* __restrict__ bias, float* __restrict__ C,
                        int M, int K, int N) {
    __shared__ short lds[4 * 4096];           // 32 KB
    short* lA_h = lds;
    short* lA_l = lds + 4096;
    short* lB_h = lds + 8192;
    short* lB_l = lds + 12288;
    int tid = threadIdx.x, lane = tid & 63, wave = tid >> 6;
    int wm = wave >> 1, wn = wave & 1;
    int q4 = lane >> 4, l15 = lane & 15;
    int m0 = blockIdx.y * 128, n0 = blockIdx.x * 128;

    f32x4 acc[4][4] = {};

    for (int k0 = 0; k0 < K; k0 += 32) {
        __syncthreads();
#pragma unroll
        for (int it = 0; it < 8; ++it) {
            int arr = it >> 1;
            int ca = ((it & 1) << 8) + tid;          // chunk within array, 0..511
            int r = ca >> 2, slot = ca & 3;
            int q = slot ^ ((r >> 1) & 3);           // xor-swizzle: conflict-free frag reads
            int grow = (arr < 2) ? (m0 + r) : (n0 + r);
            const short* gb = (arr == 0) ? Ah : (arr == 1) ? Al : (arr == 2) ? Bh : Bl;
            const short* g = gb + (size_t)grow * K + k0 + q * 8;
            int chunk_base = ((it & 1) << 8) + (wave << 6);   // wave-uniform
            short* l = lds + arr * 4096 + chunk_base * 8;
            gl_lds16(g, l);
        }
        __syncthreads();
        s16x8 a_h[4], a_l[4], b_h[4], b_l[4];
#pragma unroll
        for (int t = 0; t < 4; ++t) {
            int rA = wm * 64 + t * 16 + l15;
            int pA = rA * 4 + (q4 ^ ((rA >> 1) & 3));
            a_h[t] = *(const s16x8*)(lA_h + pA * 8);
            a_l[t] = *(const s16x8*)(lA_l + pA * 8);
            int rB = wn * 64 + t * 16 + l15;
            int pB = rB * 4 + (q4 ^ ((rB >> 1) & 3));
            b_h[t] = *(const s16x8*)(lB_h + pB * 8);
            b_l[t] = *(const s16x8*)(lB_l + pB * 8);
        }
#pragma unroll
        for (int tm = 0; tm < 4; ++tm)
#pragma unroll
            for (int tn = 0; tn < 4; ++tn) {
                acc[tm][tn] = __builtin_amdgcn_mfma_f32_16x16x32_bf16(a_h[tm], b_h[tn], acc[tm][tn], 0, 0, 0);
                acc[tm][tn] = __builtin_amdgcn_mfma_f32_16x16x32_bf16(a_h[tm], b_l[tn], acc[tm][tn], 0, 0, 0);
                acc[tm][tn] = __builtin_amdgcn_mfma_f32_16x16x32_bf16(a_l[tm], b_h[tn], acc[tm][tn], 0, 0, 0);
            }
    }
    // epilogue: C/D layout col=lane&15, row=(lane>>4)*4+reg
#pragma unroll
    for (int tm = 0; tm < 4; ++tm) {
#pragma unroll
        for (int tn = 0; tn < 4; ++tn) {
            int col = n0 + wn * 64 + tn * 16 + l15;
#pragma unroll
            for (int r = 0; r < 4; ++r) {
                int row = m0 + wm * 64 + tm * 16 + q4 * 4 + r;
                if (row < M) {
                    float v = acc[tm][tn][r] + bias[col];
                    C[(size_t)row * N + col] = fmaxf(v, 0.f);
                }
            }
        }
    }
}

// ---------------- CSR aggregation, ONE WAVE PER NODE ---------------------------------------
// Block = 256 threads = 4 waves = 4 independent nodes (N_NODES divisible by 4).
// Each lane holds F/64 floats of the row (C float4 chunks). 32 independent edge chains
// per CU (vs 8 with block-per-node) -> 4x latency overlap; scalar loads once per wave.
// Same per-node FMA order as before -> bit-identical results.
template <int F>
__global__ void k_agg_w(const float* __restrict__ in, short* __restrict__ out_hi,
                        short* __restrict__ out_lo, const int* __restrict__ row_ptr,
                        const int* __restrict__ colsrc, const float* __restrict__ normw,
                        const float* __restrict__ selfn) {
    constexpr int C = F / 256;           // float4 chunks per lane: 4 (F=1024) or 2 (F=512)
    int lane = threadIdx.x & 63;
    int w = threadIdx.x >> 6;
    int i = blockIdx.x * 4 + w;
    size_t rowo = (size_t)i * F;
    int fo = lane * 4;
    float sn = selfn[i];
    float a[C][4];
#pragma unroll
    for (int c = 0; c < C; c++) {
        float4 v = *(const float4*)(in + rowo + c * 256 + fo);
        a[c][0] = sn * v.x; a[c][1] = sn * v.y; a[c][2] = sn * v.z; a[c][3] = sn * v.w;
    }
    int e = row_ptr[i], eend = row_ptr[i + 1];
    for (; e + 1 < eend; e += 2) {
        unsigned s0 = (unsigned)colsrc[e];
        unsigned s1 = (unsigned)colsrc[e + 1];
        float w0 = normw[e], w1 = normw[e + 1];
        if (s0 >= N_NODES) { s0 = 0; w0 = 0.f; }   // defensive: poison-safe
        if (s1 >= N_NODES) { s1 = 0; w1 = 0.f; }
        float4 u0[C], u1[C];
#pragma unroll
        for (int c = 0; c < C; c++)
            u0[c] = *(const float4*)(in + (size_t)s0 * F + c * 256 + fo);
#pragma unroll
        for (int c = 0; c < C; c++)
            u1[c] = *(const float4*)(in + (size_t)s1 * F + c * 256 + fo);
#pragma unroll
        for (int c = 0; c < C; c++) {
            a[c][0] = fmaf(w0, u0[c].x, a[c][0]); a[c][1] = fmaf(w0, u0[c].y, a[c][1]);
            a[c][2] = fmaf(w0, u0[c].z, a[c][2]); a[c][3] = fmaf(w0, u0[c].w, a[c][3]);
        }
#pragma unroll
        for (int c = 0; c < C; c++) {
            a[c][0] = fmaf(w1, u1[c].x, a[c][0]); a[c][1] = fmaf(w1, u1[c].y, a[c][1]);
            a[c][2] = fmaf(w1, u1[c].z, a[c][2]); a[c][3] = fmaf(w1, u1[c].w, a[c][3]);
        }
    }
    if (e < eend) {
        unsigned s = (unsigned)colsrc[e];
        float ww = normw[e];
        if (s >= N_NODES) { s = 0; ww = 0.f; }
#pragma unroll
        for (int c = 0; c < C; c++) {
            float4 u = *(const float4*)(in + (size_t)s * F + c * 256 + fo);
            a[c][0] = fmaf(ww, u.x, a[c][0]); a[c][1] = fmaf(ww, u.y, a[c][1]);
            a[c][2] = fmaf(ww, u.z, a[c][2]); a[c][3] = fmaf(ww, u.w, a[c][3]);
        }
    }
#pragma unroll
    for (int c = 0; c < C; c++) {
        short4 hv, lv;
        hv.x = (short)f2bf_rn(a[c][0]); hv.y = (short)f2bf_rn(a[c][1]);
        hv.z = (short)f2bf_rn(a[c][2]); hv.w = (short)f2bf_rn(a[c][3]);
        lv.x = (short)f2bf_rn(a[c][0] - bf2f((unsigned short)hv.x));
        lv.y = (short)f2bf_rn(a[c][1] - bf2f((unsigned short)hv.y));
        lv.z = (short)f2bf_rn(a[c][2] - bf2f((unsigned short)hv.z));
        lv.w = (short)f2bf_rn(a[c][3] - bf2f((unsigned short)hv.w));
        *(short4*)(out_hi + rowo + c * 256 + fo) = hv;
        *(short4*)(out_lo + rowo + c * 256 + fo) = lv;
    }
}

// ---------------- mean-pool, 2-stage (double accumulation) ----------------
// Stage 1: 256 blocks = (graph, half); double partials.
__global__ void k_pool1(const float4* __restrict__ h, const int* __restrict__ gstart,
                        const int* __restrict__ gcnt, double* __restrict__ pp) {
    int g = blockIdx.x >> 1, half = blockIdx.x & 1;
    int t = threadIdx.x;
    int beg = gstart[g], cnt = gcnt[g];
    if (beg + cnt > N_NODES) cnt = N_NODES - beg;
    int c0 = cnt >> 1;
    int s = beg + (half ? c0 : 0);
    int n = half ? (cnt - c0) : c0;
    double a0 = 0, a1 = 0, a2 = 0, a3 = 0;
    for (int r = 0; r < n; r++) {
        float4 v = h[(size_t)(s + r) * 256 + t];
        a0 += v.x; a1 += v.y; a2 += v.z; a3 += v.w;
    }
    double* d = pp + (size_t)blockIdx.x * 1024 + t * 4;
    d[0] = a0; d[1] = a1; d[2] = a2; d[3] = a3;
}

// Stage 2: combine halves, divide by count.
__global__ void k_pool2(const double* __restrict__ pp, const int* __restrict__ gcnt,
                        float* __restrict__ pooled) {
    int g = blockIdx.x;
    int t = threadIdx.x;
    const double* p0 = pp + (size_t)(g * 2) * 1024 + t * 4;
    const double* p1 = p0 + 1024;
    float inv = 1.0f / fmaxf((float)gcnt[g], 1.0f);
    pooled[g * 1024 + t * 4 + 0] = (float)(p0[0] + p1[0]) * inv;
    pooled[g * 1024 + t * 4 + 1] = (float)(p0[1] + p1[1]) * inv;
    pooled[g * 1024 + t * 4 + 2] = (float)(p0[2] + p1[2]) * inv;
    pooled[g * 1024 + t * 4 + 3] = (float)(p0[3] + p1[3]) * inv;
}

// ---------------- small GEMM (M=128), 4 independent double accumulators ----------------
template <bool RELU>
__global__ void gemm_small(const float* __restrict__ A, const float* __restrict__ B,
                           const float* __restrict__ bias, float* __restrict__ C,
                           int K, int N) {
    int n = blockIdx.x * 256 + threadIdx.x;
    int m = blockIdx.y;
    if (n >= N) return;
    const float* a = A + (size_t)m * K;
    double ac0 = 0.0, ac1 = 0.0, ac2 = 0.0, ac3 = 0.0;
    for (int k = 0; k < K; k += 16) {
#pragma unroll
        for (int j = 0; j < 4; j++) {
            ac0 += (double)a[k + j]      * (double)B[(size_t)(k + j)      * N + n];
            ac1 += (double)a[k + 4 + j]  * (double)B[(size_t)(k + 4 + j)  * N + n];
            ac2 += (double)a[k + 8 + j]  * (double)B[(size_t)(k + 8 + j)  * N + n];
            ac3 += (double)a[k + 12 + j] * (double)B[(size_t)(k + 12 + j) * N + n];
        }
    }
    float r = (float)(((ac0 + ac1) + (ac2 + ac3))) + bias[n];
    if (RELU) r = fmaxf(r, 0.0f);
    C[(size_t)m * N + n] = r;
}

extern "C" void kernel_launch(void* const* d_in, const int* in_sizes, int n_in,
                              void* d_out, int out_size, void* d_ws, size_t ws_size,
                              hipStream_t stream) {
    const float* x      = (const float*)d_in[0];
    const float* eattr  = (const float*)d_in[1];
    const int*   eidx   = (const int*)d_in[2];
    const int*   batch  = (const int*)d_in[3];
    const float* emb_w1 = (const float*)d_in[4];
    const float* emb_b1 = (const float*)d_in[5];
    const float* emb_w2 = (const float*)d_in[6];
    const float* emb_b2 = (const float*)d_in[7];
    const float* ep_w1  = (const float*)d_in[8];
    const float* ep_b1  = (const float*)d_in[9];
    const float* ep_w2  = (const float*)d_in[10];
    const float* ep_b2  = (const float*)d_in[11];
    const float* c6_w   = (const float*)d_in[12];
    const float* c6_b   = (const float*)d_in[13];
    const float* c7_w   = (const float*)d_in[14];
    const float* c7_b   = (const float*)d_in[15];
    const float* c8_w   = (const float*)d_in[16];
    const float* c8_b   = (const float*)d_in[17];
    const float* fc1_w  = (const float*)d_in[18];
    const float* fc1_b  = (const float*)d_in[19];
    const float* head_w = (const float*)d_in[20];
    const float* head_b = (const float*)d_in[21];
    float* out = (float*)d_out;

    const int* src = eidx;
    const int* dst = eidx + N_EDGES;

    // ---- workspace layout (bytes) ----
    size_t off = 0;
    auto lay = [&](size_t nbytes) -> size_t {
        size_t p = off;
        off += (nbytes + 255) & ~(size_t)255;
        return p;
    };
    size_t ob0  = lay((size_t)M_PAD * 1024 * 4);   // ping: split pair (hi|lo)
    size_t ob1  = lay((size_t)M_PAD * 1024 * 4);   // pong: f32 GEMM output
    size_t oBt2 = lay((size_t)512 * 512 * 2 * 2);
    size_t oBt6 = lay((size_t)1024 * 512 * 2 * 2);
    size_t oBt7 = lay((size_t)1024 * 1024 * 2 * 2);
    size_t oBt8 = lay((size_t)1024 * 1024 * 2 * 2);
    size_t oew     = lay(N_EDGES * 4);
    size_t odis    = lay(N_NODES * 4);
    size_t oselfn  = lay(N_NODES * 4);
    size_t onormw  = lay(N_EDGES * 4);
    size_t opooled = lay((size_t)N_GRAPHS * 1024 * 4);
    size_t opp     = lay((size_t)N_GRAPHS * 2 * 1024 * 8);
    size_t oz      = lay((size_t)N_GRAPHS * 2048 * 4);
    size_t zbeg = off;
    size_t odegf   = lay(N_NODES * 4);
    size_t ocounts = lay(N_NODES * 4);
    size_t ocursor = lay(N_NODES * 4);
    size_t ogcnt   = lay(N_GRAPHS * 4);
    size_t zend = off;
    size_t orowp   = lay((N_NODES + 1) * 4);
    size_t ocolsrc = lay(N_EDGES * 4);
    size_t ogstart = lay(N_GRAPHS * 4);
    size_t obsum   = lay(64 * 4);
    size_t need_bytes = off;

    char* base = (ws_size >= need_bytes) ? (char*)d_ws : (char*)g_scratch;

    short* b0 = (short*)(base + ob0);
    float* b1f = (float*)(base + ob1);
    // split pairs (A operands) live in b0; f32 GEMM outputs live in b1
    short* S1h = b0;                       short* S1l = b0 + (size_t)M_PAD * 512;   // emb1 out
    float* S2f = b1f;                      // emb2 out f32 (512-wide)
    short* A6h = b0;                       short* A6l = b0 + (size_t)M_PAD * 512;   // agg6 out
    float* S3f = b1f;                      // conv6 out f32 (1024-wide)
    short* A7h = b0;                       short* A7l = b0 + (size_t)M_PAD * 1024;  // agg7 out
    float* S4f = b1f;                      // conv7 out f32
    short* A8h = b0;                       short* A8l = b0 + (size_t)M_PAD * 1024;  // agg8 out
    float* Y   = b1f;                      // conv8 out f32
    short* Bt2h = (short*)(base + oBt2);   short* Bt2l = Bt2h + (size_t)512 * 512;
    short* Bt6h = (short*)(base + oBt6);   short* Bt6l = Bt6h + (size_t)1024 * 512;
    short* Bt7h = (short*)(base + oBt7);   short* Bt7l = Bt7h + (size_t)1024 * 1024;
    short* Bt8h = (short*)(base + oBt8);   short* Bt8l = Bt8h + (size_t)1024 * 1024;
    float* ew     = (float*)(base + oew);
    float* dis    = (float*)(base + odis);
    float* selfn  = (float*)(base + oselfn);
    float* normw  = (float*)(base + onormw);
    float* pooled = (float*)(base + opooled);
    double* pp    = (double*)(base + opp);
    float* z      = (float*)(base + oz);
    float* degf   = (float*)(base + odegf);
    int*   counts = (int*)(base + ocounts);
    int*   cursor = (int*)(base + ocursor);
    int*   gcnt   = (int*)(base + ogcnt);
    int*   row_ptr= (int*)(base + orowp);
    int*   colsrc = (int*)(base + ocolsrc);
    int*   gstart = (int*)(base + ogstart);
    int*   bsum   = (int*)(base + obsum);

    dim3 blk(256);
    int egrid = (N_EDGES + 255) / 256;
    int ngrid = (N_NODES + 255) / 256;
    int mtiles = M_PAD / 128;           // 391
    int nb = (N_NODES + 1023) / 1024;   // 49 scan blocks
    int agrid = N_NODES / 4;            // 12500 (N_NODES divisible by 4)

    int nzero = (int)((zend - zbeg) / 4);
    k_zero<<<(nzero + 255) / 256, blk, 0, stream>>>((int*)(base + zbeg), nzero);

    // edge weights + CSR build
    k_edge_mlp<<<egrid, blk, 0, stream>>>(eattr, ep_w1, ep_b1, ep_w2, ep_b2, ew, N_EDGES);
    k_deg<<<egrid, blk, 0, stream>>>(dst, ew, degf, counts, N_EDGES);
    k_dis<<<ngrid, blk, 0, stream>>>(degf, dis, selfn, N_NODES);
    k_scan1<<<nb, blk, 0, stream>>>(counts, row_ptr, bsum, N_NODES);
    k_scan2<<<1, 64, 0, stream>>>(bsum, nb);
    k_scan3<<<ngrid, blk, 0, stream>>>(row_ptr, bsum, N_NODES);
    k_scatter<<<egrid, blk, 0, stream>>>(src, dst, ew, dis, row_ptr, cursor, colsrc, normw, N_EDGES);
    k_gcount<<<ngrid, blk, 0, stream>>>(batch, gcnt, N_NODES);
    k_gscan<<<1, 64, 0, stream>>>(gcnt, gstart);

    // weight split+transpose
    k_wsplit_t<<<dim3(512 / 32, 512 / 32), blk, 0, stream>>>(emb_w2, Bt2h, Bt2l, 512, 512);
    k_wsplit_t<<<dim3(1024 / 32, 512 / 32), blk, 0, stream>>>(c6_w, Bt6h, Bt6l, 512, 1024);
    k_wsplit_t<<<dim3(1024 / 32, 1024 / 32), blk, 0, stream>>>(c7_w, Bt7h, Bt7l, 1024, 1024);
    k_wsplit_t<<<dim3(1024 / 32, 1024 / 32), blk, 0, stream>>>(c8_w, Bt8h, Bt8l, 1024, 1024);

    // emb1 (fp32): S1 = split(relu(x@emb_w1+b1))        [b0 split]
    gemm_tile_split<<<dim3(512 / 128, mtiles), blk, 0, stream>>>(x, emb_w1, emb_b1, S1h, S1l, N_NODES, 40, 512);

    // emb2: S2f = relu(S1@emb_w2+b2) f32                [b1 f32]
    gemm_mf<<<dim3(512 / 128, mtiles), blk, 0, stream>>>(S1h, S1l, Bt2h, Bt2l, emb_b2, S2f,
                                                         N_NODES, 512, 512);

    // conv6 (agg-first): A6 = split(agg(S2f)) [b0]; S3f = relu(A6@c6_w+b6) f32 [b1]
    k_agg_w<512><<<agrid, blk, 0, stream>>>(S2f, A6h, A6l, row_ptr, colsrc, normw, selfn);
    gemm_mf<<<dim3(1024 / 128, mtiles), blk, 0, stream>>>(A6h, A6l, Bt6h, Bt6l, c6_b, S3f,
                                                          N_NODES, 512, 1024);

    // conv7: A7 = split(agg(S3f)) [b0]; S4f = relu(A7@c7_w+b7) f32 [b1]
    k_agg_w<1024><<<agrid, blk, 0, stream>>>(S3f, A7h, A7l, row_ptr, colsrc, normw, selfn);
    gemm_mf<<<dim3(1024 / 128, mtiles), blk, 0, stream>>>(A7h, A7l, Bt7h, Bt7l, c7_b, S4f,
                                                          N_NODES, 1024, 1024);

    // conv8: A8 = split(agg(S4f)) [b0]; Y = relu(A8@c8_w+b8) f32 [b1]
    k_agg_w<1024><<<agrid, blk, 0, stream>>>(S4f, A8h, A8l, row_ptr, colsrc, normw, selfn);
    gemm_mf<<<dim3(1024 / 128, mtiles), blk, 0, stream>>>(A8h, A8l, Bt8h, Bt8l, c8_b, Y,
                                                          N_NODES, 1024, 1024);

    // pool (2-stage) + head
    k_pool1<<<N_GRAPHS * 2, blk, 0, stream>>>((const float4*)Y, gstart, gcnt, pp);
    k_pool2<<<N_GRAPHS, blk, 0, stream>>>(pp, gcnt, pooled);
    gemm_small<true><<<dim3((2048 + 255) / 256, N_GRAPHS), blk, 0, stream>>>(pooled, fc1_w, fc1_b, z, 1024, 2048);
    gemm_small<false><<<dim3((345 + 255) / 256, N_GRAPHS), blk, 0, stream>>>(z, head_w, head_b, out, 2048, 345);
}

// Round 11
// 1981.492 us; speedup vs baseline: 1.2601x; 1.0052x over previous
//
#include <hip/hip_runtime.h>
#include <math.h>

#define N_NODES 50000
#define N_EDGES 200000
#define N_GRAPHS 128
#define M_PAD 50048   // N_NODES rounded up to 128

typedef short s16x8 __attribute__((ext_vector_type(8)));
typedef short s16x4 __attribute__((ext_vector_type(4)));
typedef float f32x4 __attribute__((ext_vector_type(4)));

// ---------------- persistent private scratch (allocated at dlopen, NOT in kernel_launch) ----
static void* g_scratch = nullptr;
struct ScratchInit {
    ScratchInit() {
        if (hipMalloc(&g_scratch, (size_t)704 * 1024 * 1024) != hipSuccess) g_scratch = nullptr;
    }
};
static ScratchInit g_scratch_init;

// ---------------- bf16 helpers ----------------
__device__ __forceinline__ unsigned short f2bf_rn(float x) {
    unsigned u = __float_as_uint(x);
    unsigned r = (u + 0x7FFFu + ((u >> 16) & 1u)) >> 16;
    return (unsigned short)r;
}
__device__ __forceinline__ float bf2f(unsigned short h) {
    return __uint_as_float(((unsigned)h) << 16);
}

__device__ __forceinline__ void gl_lds16(const void* g, void* l) {
    __builtin_amdgcn_global_load_lds((const __attribute__((address_space(1))) unsigned int*)g,
                                     (__attribute__((address_space(3))) unsigned int*)l, 16, 0, 0);
}

// ---------------- zero a region ----------------
__global__ void k_zero(int* __restrict__ p, int n) {
    int i = blockIdx.x * 256 + threadIdx.x;
    if (i < n) p[i] = 0;
}

// ---------------- edge-weight MLP + degree accumulation (fused) ----------------
__global__ void k_edge_deg(const float* __restrict__ ea, const float* __restrict__ w1,
                           const float* __restrict__ b1, const float* __restrict__ w2,
                           const float* __restrict__ b2, const int* __restrict__ dst,
                           float* __restrict__ ew, float* __restrict__ degf,
                           int* __restrict__ counts, int E) {
    int e = blockIdx.x * 256 + threadIdx.x;
    if (e >= E) return;
    float a0 = ea[e * 3 + 0], a1 = ea[e * 3 + 1], a2 = ea[e * 3 + 2];
    float acc = b2[0];
#pragma unroll
    for (int j = 0; j < 64; j++) {
        float h = fmaf(a0, w1[j], fmaf(a1, w1[64 + j], fmaf(a2, w1[128 + j], b1[j])));
        h = fmaxf(h, 0.0f);
        acc = fmaf(h, w2[j], acc);
    }
    float w = 1.0f / (1.0f + expf(-acc));
    ew[e] = w;
    unsigned d = (unsigned)dst[e];
    if (d >= N_NODES) return;
    atomicAdd(&degf[d], w);
    atomicAdd(&counts[d], 1);
}

// ---------------- dis/selfn + per-graph counts (fused, both N-sized) ----------------
__global__ void k_dis_gcount(const float* __restrict__ degf, float* __restrict__ dis,
                             float* __restrict__ selfn, const int* __restrict__ batch,
                             int* __restrict__ gcnt, int n) {
    int i = blockIdx.x * 256 + threadIdx.x;
    if (i >= n) return;
    float d = degf[i] + 1.0f;
    float r = (float)(1.0 / sqrt((double)d));
    dis[i] = r;
    selfn[i] = r * r;
    unsigned b = (unsigned)batch[i];
    if (b < N_GRAPHS) atomicAdd(&gcnt[b], 1);
}

// ---------------- device-wide scan (3 phases) ----------------
__global__ void k_scan1(const int* __restrict__ counts, int* __restrict__ row_ptr,
                        int* __restrict__ bsum, int n) {
    __shared__ int wsum[4];
    int b = blockIdx.x, t = threadIdx.x;
    int base = b * 1024 + t * 4;
    int v0 = 0, v1 = 0, v2 = 0, v3 = 0;
    if (base + 3 < n) {
        int4 c = *(const int4*)(counts + base);
        v0 = c.x; v1 = c.y; v2 = c.z; v3 = c.w;
    } else {
        if (base     < n) v0 = counts[base];
        if (base + 1 < n) v1 = counts[base + 1];
        if (base + 2 < n) v2 = counts[base + 2];
    }
    int tot = v0 + v1 + v2 + v3;
    int lane = t & 63, w = t >> 6;
    int x = tot;
#pragma unroll
    for (int o = 1; o < 64; o <<= 1) {
        int y = __shfl_up(x, o);
        if (lane >= o) x += y;
    }
    if (lane == 63) wsum[w] = x;
    __syncthreads();
    int wo = 0;
    for (int i = 0; i < w; i++) wo += wsum[i];
    int excl = wo + x - tot;
    int i0 = excl + v0, i1 = i0 + v1, i2 = i1 + v2, i3 = i2 + v3;
    if (base     < n) row_ptr[base + 1] = i0;
    if (base + 1 < n) row_ptr[base + 2] = i1;
    if (base + 2 < n) row_ptr[base + 3] = i2;
    if (base + 3 < n) row_ptr[base + 4] = i3;
    if (t == 255) bsum[b] = i3;
}

__global__ void k_scan2(int* __restrict__ bsum, int nb) {
    int t = threadIdx.x;
    int orig = (t < nb) ? bsum[t] : 0;
    int v = orig;
#pragma unroll
    for (int o = 1; o < 64; o <<= 1) {
        int y = __shfl_up(v, o);
        if (t >= o) v += y;
    }
    if (t < nb) bsum[t] = v - orig;
}

__global__ void k_scan3(int* __restrict__ row_ptr, const int* __restrict__ bsum, int n) {
    int i = blockIdx.x * 256 + threadIdx.x;
    if (i == 0) row_ptr[0] = 0;
    if (i < n) row_ptr[i + 1] += bsum[i >> 10];
}

// ---------------- CSR scatter ----------------
__global__ void k_scatter(const int* __restrict__ src, const int* __restrict__ dst,
                          const float* __restrict__ ew, const float* __restrict__ dis,
                          const int* __restrict__ row_ptr, int* __restrict__ cursor,
                          int* __restrict__ colsrc, float* __restrict__ normw, int E) {
    int e = blockIdx.x * 256 + threadIdx.x;
    if (e >= E) return;
    unsigned d = (unsigned)dst[e], s = (unsigned)src[e];
    if (d >= N_NODES || s >= N_NODES) return;
    int pos = row_ptr[d] + atomicAdd(&cursor[d], 1);
    if ((unsigned)pos >= N_EDGES) return;
    colsrc[pos] = (int)s;
    normw[pos] = dis[s] * ew[e] * dis[d];
}

__global__ void k_gscan(const int* __restrict__ gcnt, int* __restrict__ gstart) {
    if (threadIdx.x == 0 && blockIdx.x == 0) {
        int s = 0;
        for (int g = 0; g < N_GRAPHS; g++) { gstart[g] = s; s += gcnt[g]; }
    }
}

// ---------------- weight split+transpose: W[K][N] f32 -> Bt_hi/Bt_lo[N][K] bf16 ----------------
__global__ void k_wsplit_t(const float* __restrict__ W, short* __restrict__ Bth,
                           short* __restrict__ Btl, int K, int N) {
    __shared__ float t[32][33];
    int tx = threadIdx.x % 32, ty = threadIdx.x / 32;   // 32 x 8
    int bx = blockIdx.x, by = blockIdx.y;
#pragma unroll
    for (int i = 0; i < 4; i++) {
        int k = by * 32 + ty + i * 8;
        t[ty + i * 8][tx] = W[(size_t)k * N + bx * 32 + tx];
    }
    __syncthreads();
#pragma unroll
    for (int i = 0; i < 4; i++) {
        int n = bx * 32 + ty + i * 8;
        int k = by * 32 + tx;
        float v = t[tx][ty + i * 8];
        unsigned short h = f2bf_rn(v);
        Bth[(size_t)n * K + k] = (short)h;
        Btl[(size_t)n * K + k] = (short)f2bf_rn(v - bf2f(h));
    }
}

// ---------------- fp32 tiled GEMM (emb1), epilogue writes split bf16 ----------------
__launch_bounds__(256)
__global__ void gemm_tile_split(const float* __restrict__ A, const float* __restrict__ B,
                                const float* __restrict__ bias, short* __restrict__ Chi,
                                short* __restrict__ Clo, int M, int K, int N) {
    constexpr int BM = 128, BN = 128, BK = 8, TM = 8, TN = 8;
    __shared__ float As[BK * BM];
    __shared__ float Bs[BK * BN];
    int tid = threadIdx.x;
    int tx = tid % (BN / TN);
    int ty = tid / (BN / TN);
    int m0 = blockIdx.y * BM, n0 = blockIdx.x * BN;
    float acc[TM][TN] = {};
    int arow = tid / 2;
    int acol = (tid % 2) * 4;
    int brow = tid / 32;
    int bcol = (tid % 32) * 4;
    for (int k0 = 0; k0 < K; k0 += BK) {
        float4 av = make_float4(0.f, 0.f, 0.f, 0.f);
        int gr = m0 + arow;
        if (gr < M) av = *(const float4*)(A + (size_t)gr * K + k0 + acol);
        As[(acol + 0) * BM + arow] = av.x;
        As[(acol + 1) * BM + arow] = av.y;
        As[(acol + 2) * BM + arow] = av.z;
        As[(acol + 3) * BM + arow] = av.w;
        float4 bv = *(const float4*)(B + (size_t)(k0 + brow) * N + n0 + bcol);
        *(float4*)(Bs + brow * BN + bcol) = bv;
        __syncthreads();
#pragma unroll
        for (int kk = 0; kk < BK; kk++) {
            float a[TM], b[TN];
#pragma unroll
            for (int i = 0; i < TM; i += 4)
                *(float4*)(a + i) = *(const float4*)(As + kk * BM + ty * TM + i);
#pragma unroll
            for (int j = 0; j < TN; j += 4)
                *(float4*)(b + j) = *(const float4*)(Bs + kk * BN + tx * TN + j);
#pragma unroll
            for (int i = 0; i < TM; i++)
#pragma unroll
                for (int j = 0; j < TN; j++)
                    acc[i][j] = fmaf(a[i], b[j], acc[i][j]);
        }
        __syncthreads();
    }
#pragma unroll
    for (int i = 0; i < TM; i++) {
        int r = m0 + ty * TM + i;
        if (r >= M) continue;
#pragma unroll
        for (int j = 0; j < TN; j += 4) {
            int c = n0 + tx * TN + j;
            short4 hv, lv;
            float vv[4];
#pragma unroll
            for (int q = 0; q < 4; q++) {
                float v = acc[i][j + q] + bias[c + q];
                vv[q] = fmaxf(v, 0.f);
            }
            hv.x = (short)f2bf_rn(vv[0]); hv.y = (short)f2bf_rn(vv[1]);
            hv.z = (short)f2bf_rn(vv[2]); hv.w = (short)f2bf_rn(vv[3]);
            lv.x = (short)f2bf_rn(vv[0] - bf2f(hv.x));
            lv.y = (short)f2bf_rn(vv[1] - bf2f(hv.y));
            lv.z = (short)f2bf_rn(vv[2] - bf2f(hv.z));
            lv.w = (short)f2bf_rn(vv[3] - bf2f(hv.w));
            *(short4*)(Chi + (size_t)r * N + c) = hv;
            *(short4*)(Clo + (size_t)r * N + c) = lv;
        }
    }
}

// ---------------- bf16x3 MFMA GEMM, 128x128 tile, 256 threads -------------------------------
// A (M_PAD x K) hi/lo bf16, B^T (N x K) hi/lo bf16.  C = relu(A@B + bias) as f32.
// f32 dword-store epilogue is the proven-fast variant (r3/r8); split epilogue cost +100us.
__launch_bounds__(256)
__global__ void gemm_mf(const short* __restrict__ Ah, const short* __restrict__ Al,
                        const short* __restrict__ Bh, const short* __restrict__ Bl,
                        const float* __restrict__ bias, float* __restrict__ C,
                        int M, int K, int N) {
    __shared__ short lds[4 * 4096];           // 32 KB
    short* lA_h = lds;
    short* lA_l = lds + 4096;
    short* lB_h = lds + 8192;
    short* lB_l = lds + 12288;
    int tid = threadIdx.x, lane = tid & 63, wave = tid >> 6;
    int wm = wave >> 1, wn = wave & 1;
    int q4 = lane >> 4, l15 = lane & 15;
    int m0 = blockIdx.y * 128, n0 = blockIdx.x * 128;

    f32x4 acc[4][4] = {};

    for (int k0 = 0; k0 < K; k0 += 32) {
        __syncthreads();
#pragma unroll
        for (int it = 0; it < 8; ++it) {
            int arr = it >> 1;
            int ca = ((it & 1) << 8) + tid;          // chunk within array, 0..511
            int r = ca >> 2, slot = ca & 3;
            int q = slot ^ ((r >> 1) & 3);           // xor-swizzle: conflict-free frag reads
            int grow = (arr < 2) ? (m0 + r) : (n0 + r);
            const short* gb = (arr == 0) ? Ah : (arr == 1) ? Al : (arr == 2) ? Bh : Bl;
            const short* g = gb + (size_t)grow * K + k0 + q * 8;
            int chunk_base = ((it & 1) << 8) + (wave << 6);   // wave-uniform
            short* l = lds + arr * 4096 + chunk_base * 8;
            gl_lds16(g, l);
        }
        __syncthreads();
        s16x8 a_h[4], a_l[4], b_h[4], b_l[4];
#pragma unroll
        for (int t = 0; t < 4; ++t) {
            int rA = wm * 64 + t * 16 + l15;
            int pA = rA * 4 + (q4 ^ ((rA >> 1) & 3));
            a_h[t] = *(const s16x8*)(lA_h + pA * 8);
            a_l[t] = *(const s16x8*)(lA_l + pA * 8);
            int rB = wn * 64 + t * 16 + l15;
            int pB = rB * 4 + (q4 ^ ((rB >> 1) & 3));
            b_h[t] = *(const s16x8*)(lB_h + pB * 8);
            b_l[t] = *(const s16x8*)(lB_l + pB * 8);
        }
#pragma unroll
        for (int tm = 0; tm < 4; ++tm)
#pragma unroll
            for (int tn = 0; tn < 4; ++tn) {
                acc[tm][tn] = __builtin_amdgcn_mfma_f32_16x16x32_bf16(a_h[tm], b_h[tn], acc[tm][tn], 0, 0, 0);
                acc[tm][tn] = __builtin_amdgcn_mfma_f32_16x16x32_bf16(a_h[tm], b_l[tn], acc[tm][tn], 0, 0, 0);
                acc[tm][tn] = __builtin_amdgcn_mfma_f32_16x16x32_bf16(a_l[tm], b_h[tn], acc[tm][tn], 0, 0, 0);
            }
    }
    // epilogue: C/D layout col=lane&15, row=(lane>>4)*4+reg
#pragma unroll
    for (int tm = 0; tm < 4; ++tm) {
#pragma unroll
        for (int tn = 0; tn < 4; ++tn) {
            int col = n0 + wn * 64 + tn * 16 + l15;
#pragma unroll
            for (int r = 0; r < 4; ++r) {
                int row = m0 + wm * 64 + tm * 16 + q4 * 4 + r;
                if (row < M) {
                    float v = acc[tm][tn][r] + bias[col];
                    C[(size_t)row * N + col] = fmaxf(v, 0.f);
                }
            }
        }
    }
}

// ---------------- CSR aggregation, ONE WAVE PER NODE, NT split stores ----------------------
// Block = 256 threads = 4 waves = 4 independent nodes. Split outputs are written
// NONTEMPORAL: they are not re-read until the next GEMM (after L3 has been flushed by
// ~1 GB of GEMM traffic), so caching them only evicts the gather working set.
template <int F>
__global__ void k_agg_w(const float* __restrict__ in, short* __restrict__ out_hi,
                        short* __restrict__ out_lo, const int* __restrict__ row_ptr,
                        const int* __restrict__ colsrc, const float* __restrict__ normw,
                        const float* __restrict__ selfn) {
    constexpr int C = F / 256;           // float4 chunks per lane: 4 (F=1024) or 2 (F=512)
    int lane = threadIdx.x & 63;
    int w = threadIdx.x >> 6;
    int i = blockIdx.x * 4 + w;
    size_t rowo = (size_t)i * F;
    int fo = lane * 4;
    float sn = selfn[i];
    float a[C][4];
#pragma unroll
    for (int c = 0; c < C; c++) {
        float4 v = *(const float4*)(in + rowo + c * 256 + fo);
        a[c][0] = sn * v.x; a[c][1] = sn * v.y; a[c][2] = sn * v.z; a[c][3] = sn * v.w;
    }
    int e = row_ptr[i], eend = row_ptr[i + 1];
    for (; e + 1 < eend; e += 2) {
        unsigned s0 = (unsigned)colsrc[e];
        unsigned s1 = (unsigned)colsrc[e + 1];
        float w0 = normw[e], w1 = normw[e + 1];
        if (s0 >= N_NODES) { s0 = 0; w0 = 0.f; }
        if (s1 >= N_NODES) { s1 = 0; w1 = 0.f; }
        float4 u0[C], u1[C];
#pragma unroll
        for (int c = 0; c < C; c++)
            u0[c] = *(const float4*)(in + (size_t)s0 * F + c * 256 + fo);
#pragma unroll
        for (int c = 0; c < C; c++)
            u1[c] = *(const float4*)(in + (size_t)s1 * F + c * 256 + fo);
#pragma unroll
        for (int c = 0; c < C; c++) {
            a[c][0] = fmaf(w0, u0[c].x, a[c][0]); a[c][1] = fmaf(w0, u0[c].y, a[c][1]);
            a[c][2] = fmaf(w0, u0[c].z, a[c][2]); a[c][3] = fmaf(w0, u0[c].w, a[c][3]);
        }
#pragma unroll
        for (int c = 0; c < C; c++) {
            a[c][0] = fmaf(w1, u1[c].x, a[c][0]); a[c][1] = fmaf(w1, u1[c].y, a[c][1]);
            a[c][2] = fmaf(w1, u1[c].z, a[c][2]); a[c][3] = fmaf(w1, u1[c].w, a[c][3]);
        }
    }
    if (e < eend) {
        unsigned s = (unsigned)colsrc[e];
        float ww = normw[e];
        if (s >= N_NODES) { s = 0; ww = 0.f; }
#pragma unroll
        for (int c = 0; c < C; c++) {
            float4 u = *(const float4*)(in + (size_t)s * F + c * 256 + fo);
            a[c][0] = fmaf(ww, u.x, a[c][0]); a[c][1] = fmaf(ww, u.y, a[c][1]);
            a[c][2] = fmaf(ww, u.z, a[c][2]); a[c][3] = fmaf(ww, u.w, a[c][3]);
        }
    }
#pragma unroll
    for (int c = 0; c < C; c++) {
        s16x4 hv, lv;
        hv[0] = (short)f2bf_rn(a[c][0]); hv[1] = (short)f2bf_rn(a[c][1]);
        hv[2] = (short)f2bf_rn(a[c][2]); hv[3] = (short)f2bf_rn(a[c][3]);
        lv[0] = (short)f2bf_rn(a[c][0] - bf2f((unsigned short)hv[0]));
        lv[1] = (short)f2bf_rn(a[c][1] - bf2f((unsigned short)hv[1]));
        lv[2] = (short)f2bf_rn(a[c][2] - bf2f((unsigned short)hv[2]));
        lv[3] = (short)f2bf_rn(a[c][3] - bf2f((unsigned short)hv[3]));
        __builtin_nontemporal_store(hv, (s16x4*)(out_hi + rowo + c * 256 + fo));
        __builtin_nontemporal_store(lv, (s16x4*)(out_lo + rowo + c * 256 + fo));
    }
}

// ---------------- mean-pool, 2-stage (double accumulation) ----------------
__global__ void k_pool1(const float4* __restrict__ h, const int* __restrict__ gstart,
                        const int* __restrict__ gcnt, double* __restrict__ pp) {
    int g = blockIdx.x >> 1, half = blockIdx.x & 1;
    int t = threadIdx.x;
    int beg = gstart[g], cnt = gcnt[g];
    if (beg + cnt > N_NODES) cnt = N_NODES - beg;
    int c0 = cnt >> 1;
    int s = beg + (half ? c0 : 0);
    int n = half ? (cnt - c0) : c0;
    double a0 = 0, a1 = 0, a2 = 0, a3 = 0;
    for (int r = 0; r < n; r++) {
        float4 v = h[(size_t)(s + r) * 256 + t];
        a0 += v.x; a1 += v.y; a2 += v.z; a3 += v.w;
    }
    double* d = pp + (size_t)blockIdx.x * 1024 + t * 4;
    d[0] = a0; d[1] = a1; d[2] = a2; d[3] = a3;
}

__global__ void k_pool2(const double* __restrict__ pp, const int* __restrict__ gcnt,
                        float* __restrict__ pooled) {
    int g = blockIdx.x;
    int t = threadIdx.x;
    const double* p0 = pp + (size_t)(g * 2) * 1024 + t * 4;
    const double* p1 = p0 + 1024;
    float inv = 1.0f / fmaxf((float)gcnt[g], 1.0f);
    pooled[g * 1024 + t * 4 + 0] = (float)(p0[0] + p1[0]) * inv;
    pooled[g * 1024 + t * 4 + 1] = (float)(p0[1] + p1[1]) * inv;
    pooled[g * 1024 + t * 4 + 2] = (float)(p0[2] + p1[2]) * inv;
    pooled[g * 1024 + t * 4 + 3] = (float)(p0[3] + p1[3]) * inv;
}

// ---------------- small GEMM (M=128), 4 independent double accumulators ----------------
template <bool RELU>
__global__ void gemm_small(const float* __restrict__ A, const float* __restrict__ B,
                           const float* __restrict__ bias, float* __restrict__ C,
                           int K, int N) {
    int n = blockIdx.x * 256 + threadIdx.x;
    int m = blockIdx.y;
    if (n >= N) return;
    const float* a = A + (size_t)m * K;
    double ac0 = 0.0, ac1 = 0.0, ac2 = 0.0, ac3 = 0.0;
    for (int k = 0; k < K; k += 16) {
#pragma unroll
        for (int j = 0; j < 4; j++) {
            ac0 += (double)a[k + j]      * (double)B[(size_t)(k + j)      * N + n];
            ac1 += (double)a[k + 4 + j]  * (double)B[(size_t)(k + 4 + j)  * N + n];
            ac2 += (double)a[k + 8 + j]  * (double)B[(size_t)(k + 8 + j)  * N + n];
            ac3 += (double)a[k + 12 + j] * (double)B[(size_t)(k + 12 + j) * N + n];
        }
    }
    float r = (float)(((ac0 + ac1) + (ac2 + ac3))) + bias[n];
    if (RELU) r = fmaxf(r, 0.0f);
    C[(size_t)m * N + n] = r;
}

extern "C" void kernel_launch(void* const* d_in, const int* in_sizes, int n_in,
                              void* d_out, int out_size, void* d_ws, size_t ws_size,
                              hipStream_t stream) {
    const float* x      = (const float*)d_in[0];
    const float* eattr  = (const float*)d_in[1];
    const int*   eidx   = (const int*)d_in[2];
    const int*   batch  = (const int*)d_in[3];
    const float* emb_w1 = (const float*)d_in[4];
    const float* emb_b1 = (const float*)d_in[5];
    const float* emb_w2 = (const float*)d_in[6];
    const float* emb_b2 = (const float*)d_in[7];
    const float* ep_w1  = (const float*)d_in[8];
    const float* ep_b1  = (const float*)d_in[9];
    const float* ep_w2  = (const float*)d_in[10];
    const float* ep_b2  = (const float*)d_in[11];
    const float* c6_w   = (const float*)d_in[12];
    const float* c6_b   = (const float*)d_in[13];
    const float* c7_w   = (const float*)d_in[14];
    const float* c7_b   = (const float*)d_in[15];
    const float* c8_w   = (const float*)d_in[16];
    const float* c8_b   = (const float*)d_in[17];
    const float* fc1_w  = (const float*)d_in[18];
    const float* fc1_b  = (const float*)d_in[19];
    const float* head_w = (const float*)d_in[20];
    const float* head_b = (const float*)d_in[21];
    float* out = (float*)d_out;

    const int* src = eidx;
    const int* dst = eidx + N_EDGES;

    // ---- workspace layout (bytes) ----
    size_t off = 0;
    auto lay = [&](size_t nbytes) -> size_t {
        size_t p = off;
        off += (nbytes + 255) & ~(size_t)255;
        return p;
    };
    size_t ob0  = lay((size_t)M_PAD * 1024 * 4);   // ping: split pair (hi|lo)
    size_t ob1  = lay((size_t)M_PAD * 1024 * 4);   // pong: f32 GEMM output
    size_t oBt2 = lay((size_t)512 * 512 * 2 * 2);
    size_t oBt6 = lay((size_t)1024 * 512 * 2 * 2);
    size_t oBt7 = lay((size_t)1024 * 1024 * 2 * 2);
    size_t oBt8 = lay((size_t)1024 * 1024 * 2 * 2);
    size_t oew     = lay(N_EDGES * 4);
    size_t odis    = lay(N_NODES * 4);
    size_t oselfn  = lay(N_NODES * 4);
    size_t onormw  = lay(N_EDGES * 4);
    size_t opooled = lay((size_t)N_GRAPHS * 1024 * 4);
    size_t opp     = lay((size_t)N_GRAPHS * 2 * 1024 * 8);
    size_t oz      = lay((size_t)N_GRAPHS * 2048 * 4);
    size_t zbeg = off;
    size_t odegf   = lay(N_NODES * 4);
    size_t ocounts = lay(N_NODES * 4);
    size_t ocursor = lay(N_NODES * 4);
    size_t ogcnt   = lay(N_GRAPHS * 4);
    size_t zend = off;
    size_t orowp   = lay((N_NODES + 1) * 4);
    size_t ocolsrc = lay(N_EDGES * 4);
    size_t ogstart = lay(N_GRAPHS * 4);
    size_t obsum   = lay(64 * 4);
    size_t need_bytes = off;

    char* base = (ws_size >= need_bytes) ? (char*)d_ws : (char*)g_scratch;

    short* b0 = (short*)(base + ob0);
    float* b1f = (float*)(base + ob1);
    short* S1h = b0;                       short* S1l = b0 + (size_t)M_PAD * 512;
    float* S2f = b1f;
    short* A6h = b0;                       short* A6l = b0 + (size_t)M_PAD * 512;
    float* S3f = b1f;
    short* A7h = b0;                       short* A7l = b0 + (size_t)M_PAD * 1024;
    float* S4f = b1f;
    short* A8h = b0;                       short* A8l = b0 + (size_t)M_PAD * 1024;
    float* Y   = b1f;
    short* Bt2h = (short*)(base + oBt2);   short* Bt2l = Bt2h + (size_t)512 * 512;
    short* Bt6h = (short*)(base + oBt6);   short* Bt6l = Bt6h + (size_t)1024 * 512;
    short* Bt7h = (short*)(base + oBt7);   short* Bt7l = Bt7h + (size_t)1024 * 1024;
    short* Bt8h = (short*)(base + oBt8);   short* Bt8l = Bt8h + (size_t)1024 * 1024;
    float* ew     = (float*)(base + oew);
    float* dis    = (float*)(base + odis);
    float* selfn  = (float*)(base + oselfn);
    float* normw  = (float*)(base + onormw);
    float* pooled = (float*)(base + opooled);
    double* pp    = (double*)(base + opp);
    float* z      = (float*)(base + oz);
    float* degf   = (float*)(base + odegf);
    int*   counts = (int*)(base + ocounts);
    int*   cursor = (int*)(base + ocursor);
    int*   gcnt   = (int*)(base + ogcnt);
    int*   row_ptr= (int*)(base + orowp);
    int*   colsrc = (int*)(base + ocolsrc);
    int*   gstart = (int*)(base + ogstart);
    int*   bsum   = (int*)(base + obsum);

    dim3 blk(256);
    int egrid = (N_EDGES + 255) / 256;
    int ngrid = (N_NODES + 255) / 256;
    int mtiles = M_PAD / 128;           // 391
    int nb = (N_NODES + 1023) / 1024;   // 49 scan blocks
    int agrid = N_NODES / 4;            // 12500

    int nzero = (int)((zend - zbeg) / 4);
    k_zero<<<(nzero + 255) / 256, blk, 0, stream>>>((int*)(base + zbeg), nzero);

    // edge weights + CSR build (fused prep)
    k_edge_deg<<<egrid, blk, 0, stream>>>(eattr, ep_w1, ep_b1, ep_w2, ep_b2, dst,
                                          ew, degf, counts, N_EDGES);
    k_dis_gcount<<<ngrid, blk, 0, stream>>>(degf, dis, selfn, batch, gcnt, N_NODES);
    k_scan1<<<nb, blk, 0, stream>>>(counts, row_ptr, bsum, N_NODES);
    k_scan2<<<1, 64, 0, stream>>>(bsum, nb);
    k_scan3<<<ngrid, blk, 0, stream>>>(row_ptr, bsum, N_NODES);
    k_scatter<<<egrid, blk, 0, stream>>>(src, dst, ew, dis, row_ptr, cursor, colsrc, normw, N_EDGES);
    k_gscan<<<1, 64, 0, stream>>>(gcnt, gstart);

    // weight split+transpose
    k_wsplit_t<<<dim3(512 / 32, 512 / 32), blk, 0, stream>>>(emb_w2, Bt2h, Bt2l, 512, 512);
    k_wsplit_t<<<dim3(1024 / 32, 512 / 32), blk, 0, stream>>>(c6_w, Bt6h, Bt6l, 512, 1024);
    k_wsplit_t<<<dim3(1024 / 32, 1024 / 32), blk, 0, stream>>>(c7_w, Bt7h, Bt7l, 1024, 1024);
    k_wsplit_t<<<dim3(1024 / 32, 1024 / 32), blk, 0, stream>>>(c8_w, Bt8h, Bt8l, 1024, 1024);

    // emb1 (fp32): S1 = split(relu(x@emb_w1+b1))        [b0 split]
    gemm_tile_split<<<dim3(512 / 128, mtiles), blk, 0, stream>>>(x, emb_w1, emb_b1, S1h, S1l, N_NODES, 40, 512);

    // emb2: S2f = relu(S1@emb_w2+b2) f32                [b1 f32]
    gemm_mf<<<dim3(512 / 128, mtiles), blk, 0, stream>>>(S1h, S1l, Bt2h, Bt2l, emb_b2, S2f,
                                                         N_NODES, 512, 512);

    // conv6 (agg-first): A6 = split(agg(S2f)) [b0]; S3f = relu(A6@c6_w+b6) f32 [b1]
    k_agg_w<512><<<agrid, blk, 0, stream>>>(S2f, A6h, A6l, row_ptr, colsrc, normw, selfn);
    gemm_mf<<<dim3(1024 / 128, mtiles), blk, 0, stream>>>(A6h, A6l, Bt6h, Bt6l, c6_b, S3f,
                                                          N_NODES, 512, 1024);

    // conv7: A7 = split(agg(S3f)) [b0]; S4f = relu(A7@c7_w+b7) f32 [b1]
    k_agg_w<1024><<<agrid, blk, 0, stream>>>(S3f, A7h, A7l, row_ptr, colsrc, normw, selfn);
    gemm_mf<<<dim3(1024 / 128, mtiles), blk, 0, stream>>>(A7h, A7l, Bt7h, Bt7l, c7_b, S4f,
                                                          N_NODES, 1024, 1024);

    // conv8: A8 = split(agg(S4f)) [b0]; Y = relu(A8@c8_w+b8) f32 [b1]
    k_agg_w<1024><<<agrid, blk, 0, stream>>>(S4f, A8h, A8l, row_ptr, colsrc, normw, selfn);
    gemm_mf<<<dim3(1024 / 128, mtiles), blk, 0, stream>>>(A8h, A8l, Bt8h, Bt8l, c8_b, Y,
                                                          N_NODES, 1024, 1024);

    // pool (2-stage) + head
    k_pool1<<<N_GRAPHS * 2, blk, 0, stream>>>((const float4*)Y, gstart, gcnt, pp);
    k_pool2<<<N_GRAPHS, blk, 0, stream>>>(pp, gcnt, pooled);
    gemm_small<true><<<dim3((2048 + 255) / 256, N_GRAPHS), blk, 0, stream>>>(pooled, fc1_w, fc1_b, z, 1024, 2048);
    gemm_small<false><<<dim3((345 + 255) / 256, N_GRAPHS), blk, 0, stream>>>(z, head_w, head_b, out, 2048, 345);
}